// Round 7
// baseline (1337.609 us; speedup 1.0000x reference)
//
#include <hip/hip_runtime.h>
#include <hip/hip_bf16.h>

#define NN 50000
#define NE 800000

typedef __bf16 bf16x8 __attribute__((ext_vector_type(8)));
typedef float f4v __attribute__((ext_vector_type(4)));

__device__ __forceinline__ float silu_f(float v){
  return v*__builtin_amdgcn_rcpf(1.0f+__expf(-v));
}
__device__ __forceinline__ float bf2f(unsigned int u){ return __uint_as_float(u<<16); }
__device__ __forceinline__ unsigned bfr(float f){
  unsigned b = __float_as_uint(f);
  return b + 0x7fffu + ((b>>16)&1u);
}
__device__ __forceinline__ unsigned short f2bf(float f){ return (unsigned short)(bfr(f)>>16); }
__device__ __forceinline__ unsigned pk2(float a, float b){
  unsigned r;
  asm("v_cvt_pk_bf16_f32 %0, %1, %2" : "=v"(r) : "v"(a), "v"(b));
  return r;
}

union U8 { unsigned short us[8]; uint4 u4; };

__device__ __forceinline__ void pack8(unsigned short* dst, float4 a, float4 b){
  uint4 u;
  u.x = pk2(a.x,a.y); u.y = pk2(a.z,a.w);
  u.z = pk2(b.x,b.y); u.w = pk2(b.z,b.w);
  *(uint4*)dst = u;
}

// short-index of 16B chunk c of row e in a row-major swizzled activation buffer
__device__ __forceinline__ int lidx(int e, int c, int CH){
  return (e*CH + ((c & ~7) | ((c ^ e) & 7))) << 3;
}

// 8-wave GEMM: wave covers outcol-quarter q (32 cols) and edge-tile pair {eb, eb+1}
template<int KC, int CH>
__device__ __forceinline__ void gemm8(const unsigned short* act, const unsigned short* wf,
                                      int q, int eb, int lane, f4v (&acc)[2][2]){
  int le = lane & 15, quad = lane >> 4;
  #pragma unroll
  for (int kc=0;kc<KC;kc++){
    bf16x8 a0 = *(const bf16x8*)(wf + (((q*2  )*KC + kc)<<9) + lane*8);
    bf16x8 a1 = *(const bf16x8*)(wf + (((q*2+1)*KC + kc)<<9) + lane*8);
    int chunk = kc*4 + quad;
    #pragma unroll
    for (int e2=0;e2<2;e2++){
      bf16x8 b = *(const bf16x8*)(act + lidx((eb+e2)*16+le, chunk, CH));
      acc[e2][0] = __builtin_amdgcn_mfma_f32_16x16x32_bf16(a0, b, acc[e2][0], 0,0,0);
      acc[e2][1] = __builtin_amdgcn_mfma_f32_16x16x32_bf16(a1, b, acc[e2][1], 0,0,0);
    }
  }
}

// 8-wave epilogue: D regs -> row-major swizzled bf16 buffer (et range {eb,eb+1})
template<int CH, bool SILU, bool BIAS>
__device__ __forceinline__ void epi8(unsigned short* dst, const f4v (&acc)[2][2],
                                     const float* bias, int q, int eb, int lane){
  int le = lane & 15, quad = lane >> 4;
  #pragma unroll
  for (int ot=0; ot<2; ot++){
    float4 bv = make_float4(0,0,0,0);
    if (BIAS) bv = *(const float4*)(bias + q*32 + ot*16 + quad*4);
    int chunk = q*4 + ot*2 + (quad>>1);
    int soff = (quad&1)*4;
    #pragma unroll
    for (int e2=0; e2<2; e2++){
      float v0=acc[e2][ot][0], v1=acc[e2][ot][1], v2=acc[e2][ot][2], v3=acc[e2][ot][3];
      if (BIAS){ v0+=bv.x; v1+=bv.y; v2+=bv.z; v3+=bv.w; }
      if (SILU){ v0=silu_f(v0); v1=silu_f(v1); v2=silu_f(v2); v3=silu_f(v3); }
      uint2 u; u.x = pk2(v0,v1); u.y = pk2(v2,v3);
      *(uint2*)(dst + lidx((eb+e2)*16+le, chunk, CH) + soff) = u;
    }
  }
}

// head reduction as MFMA: out[h][e] = sum_k W[k][h]*act[e][k]; hu = edge-tile unit 0..3
template<int CH>
__device__ __forceinline__ void mfma_head(const unsigned short* buf, const unsigned short* whf,
                                          int hu, int lane, float* dst /*[4*65]*/){
  int le = lane & 15, quad = lane >> 4;
  f4v hacc = {0.f,0.f,0.f,0.f};
  #pragma unroll
  for (int kc=0;kc<4;kc++){
    bf16x8 a = *(const bf16x8*)(whf + (kc<<9) + lane*8);
    bf16x8 b = *(const bf16x8*)(buf + lidx(hu*16+le, kc*4+quad, CH));
    hacc = __builtin_amdgcn_mfma_f32_16x16x32_bf16(a, b, hacc, 0,0,0);
  }
  if (quad==0){
    #pragma unroll
    for (int r=0;r<4;r++) dst[r*65 + hu*16 + le] = hacc[r];
  }
}

// ---------------- zero a span ----------------
__global__ __launch_bounds__(256) void k_zero(float* __restrict__ p, int n){
  int i = blockIdx.x*256 + threadIdx.x;
  if (i < n) p[i] = 0.f;
}

// ---------------- fold ew2@eww into W' [128][4], bias' -> stats[12..15] ----------------
__global__ __launch_bounds__(256) void k_wcomb(const float* __restrict__ ew2, const float* __restrict__ eww,
                                               const float* __restrict__ eb2, const float* __restrict__ ewb,
                                               const float* __restrict__ pb2,
                                               float* __restrict__ wcomb, float* __restrict__ stats){
  int t = threadIdx.x;
  #pragma unroll
  for (int o=t;o<512;o+=256){
    int i=o>>2, hh=o&3;
    float s=0.f;
    for (int j=0;j<128;j++) s += ew2[i*128+j]*eww[j*4+hh];
    wcomb[o]=s;
  }
  if (t<4){
    float s=0.f;
    for (int j=0;j<128;j++) s += eb2[j]*eww[j*4+t];
    stats[12+t] = s + ewb[t] + pb2[t];
  }
}

// fold A(128x128)@B(128x128): dstW[i][n]=sum_j A[i][j]*B[j][n]; row 128 -> bias fold
__global__ __launch_bounds__(256) void k_wfold(const float* __restrict__ A, const float* __restrict__ Bm,
                                               const float* __restrict__ abias, const float* __restrict__ b2,
                                               float* __restrict__ dstW, float* __restrict__ dstB){
  int idx = blockIdx.x*256 + threadIdx.x;
  if (idx >= 129*128) return;
  int i = idx>>7, n = idx&127;
  if (i<128){
    float s=0.f;
    for (int j=0;j<128;j++) s += A[i*128+j]*Bm[j*128+n];
    dstW[i*128+n]=s;
  } else {
    float s=b2[n];
    for (int j=0;j<128;j++) s += abias[j]*Bm[j*128+n];
    dstB[n]=s;
  }
}

// fold ew2@mw1[0:128] -> rows 0..127; mw1 extras rows at K=144..153; rest zero.
__global__ __launch_bounds__(256) void k_wfoldm(const float* __restrict__ ew2, const float* __restrict__ mw1,
                                                const float* __restrict__ eb2, const float* __restrict__ mb1,
                                                float* __restrict__ dstW, float* __restrict__ dstB){
  int idx = blockIdx.x*256 + threadIdx.x;
  if (idx >= 161*128) return;
  int i = idx>>7, n = idx&127;
  if (i<128){
    float s=0.f;
    for (int j=0;j<128;j++) s += ew2[i*128+j]*mw1[j*128+n];
    dstW[i*128+n]=s;
  } else if (i<160){
    int r = i-144;
    dstW[i*128+n] = (r>=0 && r<10) ? mw1[(128+r)*128+n] : 0.f;
  } else {
    float s=mb1[n];
    for (int j=0;j<128;j++) s += eb2[j]*mw1[j*128+n];
    dstB[n]=s;
  }
}

// fold mw2@gw -> [128][4]; row 128 -> bg'
__global__ __launch_bounds__(256) void k_wfoldg(const float* __restrict__ mw2, const float* __restrict__ gw,
                                                const float* __restrict__ mb2, const float* __restrict__ gb,
                                                float* __restrict__ dstW, float* __restrict__ dstB){
  int idx = blockIdx.x*256 + threadIdx.x;
  if (idx >= 129*4) return;
  int i = idx>>2, hh = idx&3;
  if (i<128){
    float s=0.f;
    for (int j=0;j<128;j++) s += mw2[i*128+j]*gw[j*4+hh];
    dstW[i*4+hh]=s;
  } else {
    float s=gb[hh];
    for (int j=0;j<128;j++) s += mb2[j]*gw[j*4+hh];
    dstB[hh]=s;
  }
}

// ---------------- weight pre-pack into MFMA fragment order (bf16) ----------------
__global__ __launch_bounds__(256) void k_wprep(const float* __restrict__ src, unsigned short* __restrict__ dst,
                                               int Kreal, int KC){
  int idx = blockIdx.x*256 + threadIdx.x;
  int tot = 8*KC*512;
  if (idx >= tot) return;
  int nt  = idx/(KC*512); int rem = idx%(KC*512);
  int kc  = rem>>9;       int r2  = rem&511;
  int lq  = r2>>3;        int j   = r2&7;
  int k   = kc*32 + (lq>>4)*8 + j;
  int n   = nt*16 + (lq&15);
  float v = (k < Kreal) ? src[k*128 + n] : 0.f;
  dst[idx] = f2bf(v);
}

// qkv weight [64][256] -> 16-tile A-frag, KC=2
__global__ __launch_bounds__(256) void k_wprepq(const float* __restrict__ src, unsigned short* __restrict__ dst){
  int idx = blockIdx.x*256 + threadIdx.x;
  if (idx >= 16384) return;
  int nt  = idx>>10;  int rem = idx&1023;
  int kc  = rem>>9;   int r2  = rem&511;
  int lq  = r2>>3;    int j   = r2&7;
  int k   = kc*32 + (lq>>4)*8 + j;
  int n   = nt*16 + (lq&15);
  dst[idx] = f2bf(src[k*256 + n]);
}

// head-matrix [128][4] -> A-frag (M padded 4->16), KC=4
__global__ __launch_bounds__(256) void k_wprep4(const float* __restrict__ src, unsigned short* __restrict__ dst){
  int idx = blockIdx.x*256 + threadIdx.x;
  if (idx >= 2048) return;
  int kc = idx>>9; int r2 = idx&511; int lq = r2>>3; int j = r2&7;
  int k = kc*32 + (lq>>4)*8 + j;
  int n = lq&15;
  dst[idx] = f2bf((n<4) ? src[k*4+n] : 0.f);
}

// ---------------- stats ----------------
__global__ __launch_bounds__(256) void k_stats(const float* __restrict__ x, float* __restrict__ stats){
  int i = blockIdx.x*256 + threadIdx.x;
  float v0=0.f,v1=0.f,v2=0.f;
  if (i < NN){ v0=x[i*3+0]; v1=x[i*3+1]; v2=x[i*3+2]; }
  float vals[6] = {v0,v1,v2,v0*v0,v1*v1,v2*v2};
  __shared__ float red[256];
  for (int c=0;c<6;c++){
    red[threadIdx.x]=vals[c];
    __syncthreads();
    for (int off=128; off>0; off>>=1){
      if (threadIdx.x < off) red[threadIdx.x] += red[threadIdx.x+off];
      __syncthreads();
    }
    if (threadIdx.x==0) atomicAdd(&stats[c], red[0]);
    __syncthreads();
  }
}

__global__ __launch_bounds__(64) void k_statsfin(float* __restrict__ stats){
  int t = threadIdx.x;
  if (t < 3){
    float s = stats[t], sq = stats[3+t];
    float mean = s/(float)NN;
    float var = (sq - s*s/(float)NN)/(float)(NN-1);
    float sd = sqrtf(var);
    stats[6+t] = mean;
    stats[9+t] = 1.0f/(sd + 1e-8f);
  }
}

// ---------------- qkv via MFMA ----------------
__global__ __launch_bounds__(256) void k_qkv2(const float* __restrict__ h,
    const unsigned short* __restrict__ wqf,
    const float* __restrict__ bq, const float* __restrict__ bk, const float* __restrict__ bv,
    unsigned short* __restrict__ q, unsigned short* __restrict__ kk, unsigned short* __restrict__ v){
  __shared__ __align__(16) unsigned short hstage[64*8*8];
  int t = threadIdx.x; int lane = t & 63; int w = t >> 6;
  int wu = __builtin_amdgcn_readfirstlane(w);
  int r0 = blockIdx.x*64;
  {
    int row = r0 + lane;
    float4 a = make_float4(0,0,0,0), b2 = make_float4(0,0,0,0),
           c = make_float4(0,0,0,0), d2 = make_float4(0,0,0,0);
    if (row < NN){
      const float* hr = h + (size_t)row*64 + wu*16;
      a  = *(const float4*)(hr);    b2 = *(const float4*)(hr+4);
      c  = *(const float4*)(hr+8);  d2 = *(const float4*)(hr+12);
    }
    pack8(&hstage[lidx(lane, 2*wu,   8)], a, b2);
    pack8(&hstage[lidx(lane, 2*wu+1, 8)], c, d2);
  }
  __syncthreads();
  int le = lane & 15, quad = lane >> 4;
  #pragma unroll
  for (int ti=0; ti<12; ti++){
    int tt = ti*4 + wu;
    f4v acc[4];
    f4v z = {0.f,0.f,0.f,0.f};
    acc[0]=z; acc[1]=z; acc[2]=z; acc[3]=z;
    #pragma unroll
    for (int kc=0;kc<2;kc++){
      bf16x8 a = *(const bf16x8*)(wqf + ((tt*2 + kc)<<9) + lane*8);
      int chunk = kc*4 + quad;
      #pragma unroll
      for (int et=0;et<4;et++){
        bf16x8 b = *(const bf16x8*)(hstage + lidx(et*16+le, chunk, 8));
        acc[et] = __builtin_amdgcn_mfma_f32_16x16x32_bf16(a, b, acc[et], 0,0,0);
      }
    }
    int mat = tt>>4; int ct = tt&15;
    const float* bias = (mat==0)? bq : (mat==1)? bk : bv;
    unsigned short* outp = (mat==0)? q : (mat==1)? kk : v;
    float4 bv4 = *(const float4*)(bias + ct*16 + quad*4);
    int col = ct*16 + quad*4;
    #pragma unroll
    for (int et=0;et<4;et++){
      int row2 = r0 + et*16 + le;
      if (row2 < NN){
        float v0=acc[et][0]+bv4.x, v1=acc[et][1]+bv4.y, v2=acc[et][2]+bv4.z, v3=acc[et][3]+bv4.w;
        if (mat<2){
          uint2 u; u.x = pk2(v0,v1); u.y = pk2(v2,v3);
          *(uint2*)(outp + (size_t)row2*256 + col) = u;
        } else {
          int head = col>>6, dd = col&63;
          unsigned short* vp = outp + (size_t)row2*256 + (size_t)dd*4 + head;
          vp[0]  = f2bf(v0);
          vp[4]  = f2bf(v1);
          vp[8]  = f2bf(v2);
          vp[12] = f2bf(v3);
        }
      }
    }
  }
}

// ---------------- CSR build ----------------
__global__ __launch_bounds__(256) void k_count(const int* __restrict__ ei, int* __restrict__ counts){
  int e = blockIdx.x*256 + threadIdx.x;
  if (e < NE) atomicAdd(&counts[ei[e]], 1);
}

__global__ __launch_bounds__(256) void k_scan(int* __restrict__ counts, int* __restrict__ offs){
  __shared__ int ps[256];
  int t = threadIdx.x;
  int base = t*196;
  int s = 0;
  for (int i=0;i<196;i++){ int idx = base+i; if (idx < NN) s += counts[idx]; }
  ps[t]=s; __syncthreads();
  for (int off=1; off<256; off<<=1){
    int vv = (t>=off)? ps[t-off] : 0;
    __syncthreads();
    ps[t]+=vv;
    __syncthreads();
  }
  int run = ps[t]-s;
  for (int i=0;i<196;i++){
    int idx = base+i;
    if (idx < NN){ int c = counts[idx]; offs[idx]=run; counts[idx]=run; run+=c; }
  }
  if (t==255) offs[NN]=run;
}

__global__ __launch_bounds__(256) void k_fill(const int* __restrict__ ei, int* __restrict__ cursor, int* __restrict__ elist){
  int e = blockIdx.x*256 + threadIdx.x;
  if (e < NE){
    int r = ei[e];
    int p = atomicAdd(&cursor[r],1);
    elist[p] = e;
  }
}

// ---------------- E1: 8-wave (512 threads), 4 blocks/CU target ----------------
__global__ __launch_bounds__(512, 8) void k_e1(
    const float* __restrict__ h, const float* __restrict__ x, const int* __restrict__ ei,
    const float* __restrict__ stats,
    const unsigned short* __restrict__ qb, const unsigned short* __restrict__ kb,
    const unsigned short* __restrict__ wfrag, const unsigned short* __restrict__ whfrag,
    const float* __restrict__ eb1,
    const float* __restrict__ pw1, const float* __restrict__ pb1,
    const float* __restrict__ pw2,
    float* __restrict__ asum, float* __restrict__ eattn){
  __shared__ __align__(16) unsigned short bufIn[64*24*8];
  __shared__ float logit_s[256];
  __shared__ float ewt2_s[4*65];
  __shared__ float pos_s[4*65];
  __shared__ float rd_s[64], xnr_s[192], xnc_s[192];
  __shared__ int row_s[64], col_s[64];
  int t = threadIdx.x; int lane = t & 63; int w = t >> 6;
  int wu = __builtin_amdgcn_readfirstlane(w);
  int q = wu & 3, eb = (wu>>2)*2;
  int ebase = blockIdx.x * 64;

  for (int i=t;i<260;i+=512) pos_s[i]=0.f;
  if (t < 64){
    int ge = ebase + t;
    int r = ei[ge], c = ei[NE+ge];
    row_s[t]=r; col_s[t]=c;
    float xr0=x[r*3],xr1=x[r*3+1],xr2=x[r*3+2];
    float xc0=x[c*3],xc1=x[c*3+1],xc2=x[c*3+2];
    float rp0=xr0-xc0, rp1=xr1-xc1, rp2=xr2-xc2;
    rd_s[t]=rp0*rp0+rp1*rp1+rp2*rp2;
    float m0=stats[6],m1=stats[7],m2=stats[8],s0=stats[9],s1=stats[10],s2=stats[11];
    xnr_s[t*3+0]=(xr0-m0)*s0; xnr_s[t*3+1]=(xr1-m1)*s1; xnr_s[t*3+2]=(xr2-m2)*s2;
    xnc_s[t*3+0]=(xc0-m0)*s0; xnc_s[t*3+1]=(xc1-m1)*s1; xnc_s[t*3+2]=(xc2-m2)*s2;
  }
  __syncthreads();

  // q.k dots: 8 edges per wave
  for (int ii=0; ii<8; ii++){
    int e = wu*8+ii;
    int r = row_s[e], c = col_s[e];
    uint2 qu = *(const uint2*)(qb + (size_t)r*256 + lane*4);
    uint2 ku = *(const uint2*)(kb + (size_t)c*256 + lane*4);
    float d = bf2f(qu.x&0xffffu)*bf2f(ku.x&0xffffu)
            + bf2f(qu.x>>16)   *bf2f(ku.x>>16)
            + bf2f(qu.y&0xffffu)*bf2f(ku.y&0xffffu)
            + bf2f(qu.y>>16)   *bf2f(ku.y>>16);
    d += __shfl_xor(d,1,16); d += __shfl_xor(d,2,16);
    d += __shfl_xor(d,4,16); d += __shfl_xor(d,8,16);
    if ((lane&15)==0) logit_s[e*4 + (lane>>4)] = d*0.125f;
  }
  // pos_enc partials: 8 j-slices of 8
  {
    int jb = wu*8;
    float rd = rd_s[lane];
    float p0=0,p1=0,p2=0,p3=0;
    for (int j=jb; j<jb+8; j++){
      float hp = rd*pw1[j] + pb1[j];
      float hs = silu_f(hp);
      const float4 w4 = *(const float4*)(pw2 + j*4);
      p0+=hs*w4.x; p1+=hs*w4.y; p2+=hs*w4.z; p3+=hs*w4.w;
    }
    atomicAdd(&pos_s[0*65+lane],p0);
    atomicAdd(&pos_s[1*65+lane],p1);
    atomicAdd(&pos_s[2*65+lane],p2);
    atomicAdd(&pos_s[3*65+lane],p3);
  }
  // stage: waves 0..3 h[row] slices, waves 4..7 h[col] slices
  if (wu < 4){
    const float* hr = h + (size_t)row_s[lane]*64 + wu*16;
    pack8(&bufIn[lidx(lane, 2*wu,   24)], *(const float4*)(hr),   *(const float4*)(hr+4));
    pack8(&bufIn[lidx(lane, 2*wu+1, 24)], *(const float4*)(hr+8), *(const float4*)(hr+12));
  } else {
    int s = wu-4;
    const float* hc = h + (size_t)col_s[lane]*64 + s*16;
    pack8(&bufIn[lidx(lane, 8+2*s, 24)], *(const float4*)(hc),   *(const float4*)(hc+4));
    pack8(&bufIn[lidx(lane, 9+2*s, 24)], *(const float4*)(hc+8), *(const float4*)(hc+12));
  }
  if (t < 64){
    pack8(&bufIn[lidx(t,16,24)],
          make_float4(rd_s[t], xnr_s[t*3+0], xnr_s[t*3+1], xnr_s[t*3+2]),
          make_float4(xnc_s[t*3+0], xnc_s[t*3+1], xnc_s[t*3+2], 0.f));
  }
  {
    uint4 z4 = make_uint4(0,0,0,0);
    int e = t&63, j = t>>6;
    if (j < 3) *(uint4*)&bufIn[lidx(e, 17+j, 24)] = z4;
  }
  __syncthreads();
  f4v acc[2][2];
  f4v z = {0.f,0.f,0.f,0.f};
  acc[0][0]=z; acc[0][1]=z; acc[1][0]=z; acc[1][1]=z;
  gemm8<5,24>(bufIn, wfrag + 0, q, eb, lane, acc);
  __syncthreads();            // all waves done reading bufIn before overwrite
  epi8<24,true,true>(bufIn, acc, eb1, q, eb, lane);
  __syncthreads();
  if (wu < 4) mfma_head<24>(bufIn, whfrag + 0, wu, lane, ewt2_s);
  __syncthreads();
  if (t < 256){
    int e2 = t>>2, hh = t&3;
    float lg = logit_s[t] + stats[12+hh] + ewt2_s[hh*65+e2] + pos_s[hh*65+e2];
    float ex = __expf(lg);
    eattn[(size_t)ebase*4 + t] = ex;
    atomicAdd(&asum[row_s[e2]*4 + hh], ex);
  }
}

// ---------------- E2: 8-wave (512 threads), folded, ping-pong ----------------
__global__ __launch_bounds__(512, 6) void k_e2(
    const float* __restrict__ h, const float* __restrict__ x, const int* __restrict__ ei,
    const float* __restrict__ stats,
    const float* __restrict__ asum, const float* __restrict__ eattn,
    const unsigned short* __restrict__ wfrag, const unsigned short* __restrict__ whfrag,
    const float* __restrict__ eb1, const float* __restrict__ fbias, // [0]=bm' [128]=bc' [256]=bx' [384..387]=bg'
    const float* __restrict__ cb2, const float* __restrict__ coordw,
    const float* __restrict__ xb2,
    float* __restrict__ cvec){
  __shared__ __align__(16) unsigned short bufIn[64*24*8];
  __shared__ __align__(16) unsigned short bufA [64*16*8];
  __shared__ float g_s[4*65], c_s[4*65], xx_s[4*65];
  __shared__ float s_s[64], cs_s[64];
  __shared__ float rp_s[192], rd_s[64], xnr_s[192], xnc_s[192], xc_s[192];
  __shared__ int row_s[64], col_s[64];
  int t = threadIdx.x; int lane = t & 63; int w = t >> 6;
  int wu = __builtin_amdgcn_readfirstlane(w);
  int q = wu & 3, eb = (wu>>2)*2;
  int ebase = blockIdx.x * 64;

  float am = 0.f;
  if (t < 64){
    int ge = ebase + t;
    int r = ei[ge], c = ei[NE+ge];
    row_s[t]=r; col_s[t]=c;
    // prefetch attn/asum early: latency hides under geometry + staging
    float4 at = *(const float4*)(eattn + (size_t)ge*4);
    const float* as4 = asum + (size_t)r*4;
    float a0=as4[0],a1=as4[1],a2=as4[2],a3=as4[3];
    float xr0=x[r*3],xr1=x[r*3+1],xr2=x[r*3+2];
    float xc0=x[c*3],xc1=x[c*3+1],xc2=x[c*3+2];
    float rp0=xr0-xc0, rp1=xr1-xc1, rp2=xr2-xc2;
    rp_s[t*3+0]=rp0; rp_s[t*3+1]=rp1; rp_s[t*3+2]=rp2;
    rd_s[t]=rp0*rp0+rp1*rp1+rp2*rp2;
    xc_s[t*3+0]=xc0; xc_s[t*3+1]=xc1; xc_s[t*3+2]=xc2;
    float m0=stats[6],m1=stats[7],m2=stats[8],s0=stats[9],s1=stats[10],s2=stats[11];
    xnr_s[t*3+0]=(xr0-m0)*s0; xnr_s[t*3+1]=(xr1-m1)*s1; xnr_s[t*3+2]=(xr2-m2)*s2;
    xnc_s[t*3+0]=(xc0-m0)*s0; xnc_s[t*3+1]=(xc1-m1)*s1; xnc_s[t*3+2]=(xc2-m2)*s2;
    am = 0.25f*( at.x/(a0+1e-8f) + at.y/(a1+1e-8f)
               + at.z/(a2+1e-8f) + at.w/(a3+1e-8f) );
  }
  __syncthreads();
  // stage h[row] (waves 0..3) / h[col] (waves 4..7)
  if (wu < 4){
    const float* hr = h + (size_t)row_s[lane]*64 + wu*16;
    pack8(&bufIn[lidx(lane, 2*wu,   24)], *(const float4*)(hr),   *(const float4*)(hr+4));
    pack8(&bufIn[lidx(lane, 2*wu+1, 24)], *(const float4*)(hr+8), *(const float4*)(hr+12));
  } else {
    int s = wu-4;
    const float* hc = h + (size_t)col_s[lane]*64 + s*16;
    pack8(&bufIn[lidx(lane, 8+2*s, 24)], *(const float4*)(hc),   *(const float4*)(hc+4));
    pack8(&bufIn[lidx(lane, 9+2*s, 24)], *(const float4*)(hc+8), *(const float4*)(hc+12));
  }
  // extras: chunk16 = edge_attr extras; chunk17 zeros; chunks 18,19 = m_in extras
  if (t < 64){
    pack8(&bufIn[lidx(t,16,24)],
          make_float4(rd_s[t], xnr_s[t*3+0], xnr_s[t*3+1], xnr_s[t*3+2]),
          make_float4(xnc_s[t*3+0], xnc_s[t*3+1], xnc_s[t*3+2], 0.f));
    *(uint4*)&bufIn[lidx(t,17,24)] = make_uint4(0,0,0,0);
    pack8(&bufIn[lidx(t,18,24)],
          make_float4(am, rp_s[t*3+0], rp_s[t*3+1], rp_s[t*3+2]),
          make_float4(xnr_s[t*3+0], xnr_s[t*3+1], xnr_s[t*3+2], xnc_s[t*3+0]));
    pack8(&bufIn[lidx(t,19,24)],
          make_float4(xnc_s[t*3+1], xnc_s[t*3+2], 0.f, 0.f),
          make_float4(0.f,0.f,0.f,0.f));
  }
  __syncthreads();
  f4v acc[2][2], ax[2][2];
  f4v z = {0.f,0.f,0.f,0.f};
  // G1: ew1 (KC=5, zeros beyond K=135) -> u1 = silu(+eb1) -> bufA
  acc[0][0]=z; acc[0][1]=z; acc[1][0]=z; acc[1][1]=z;
  gemm8<5,24>(bufIn, wfrag + 0, q, eb, lane, acc);
  epi8<16,true,true>(bufA, acc, eb1, q, eb, lane);
  __syncthreads();
  // G3': mw1' — kc 0..3 from bufA (u1), kc 4 from bufIn chunks 16..19 (extras)
  acc[0][0]=z; acc[0][1]=z; acc[1][0]=z; acc[1][1]=z;
  {
    const unsigned short* wf = wfrag + 20480;
    int le = lane&15, quad = lane>>4;
    #pragma unroll
    for (int kc=0;kc<5;kc++){
      bf16x8 a0 = *(const bf16x8*)(wf + (((q*2  )*5 + kc)<<9) + lane*8);
      bf16x8 a1 = *(const bf16x8*)(wf + (((q*2+1)*5 + kc)<<9) + lane*8);
      int chunk = kc*4 + quad;
      #pragma unroll
      for (int e2=0;e2<2;e2++){
        bf16x8 b = (kc<4) ? *(const bf16x8*)(bufA  + lidx((eb+e2)*16+le, chunk, 16))
                          : *(const bf16x8*)(bufIn + lidx((eb+e2)*16+le, chunk, 24));
        acc[e2][0] = __builtin_amdgcn_mfma_f32_16x16x32_bf16(a0, b, acc[e2][0], 0,0,0);
        acc[e2][1] = __builtin_amdgcn_mfma_f32_16x16x32_bf16(a1, b, acc[e2][1], 0,0,0);
      }
    }
  }
  // u -> bufIn 0..15 (safe: G3' readers touch only bufA + bufIn chunks 16..19)
  epi8<24,true,true>(bufIn, acc, fbias + 0, q, eb, lane);
  __syncthreads();
  // gates head (waves 0..3, read-only on u) + G5/G6 folded cw1'/xw1' (all waves)
  if (wu < 4) mfma_head<24>(bufIn, whfrag + 2048, wu, lane, g_s);
  acc[0][0]=z; acc[0][1]=z; acc[1][0]=z; acc[1][1]=z;
  ax[0][0]=z; ax[0][1]=z; ax[1][0]=z; ax[1][1]=z;
  {
    const unsigned short* wfc = wfrag + 40960;
    const unsigned short* wfx = wfrag + 57344;
    int le = lane&15, quad = lane>>4;
    #pragma unroll
    for (int kc=0;kc<4;kc++){
      bf16x8 ac0 = *(const bf16x8*)(wfc + (((q*2  )*4 + kc)<<9) + lane*8);
      bf16x8 ac1 = *(const bf16x8*)(wfc + (((q*2+1)*4 + kc)<<9) + lane*8);
      bf16x8 ax0 = *(const bf16x8*)(wfx + (((q*2  )*4 + kc)<<9) + lane*8);
      bf16x8 ax1 = *(const bf16x8*)(wfx + (((q*2+1)*4 + kc)<<9) + lane*8);
      int chunk = kc*4 + quad;
      #pragma unroll
      for (int e2=0;e2<2;e2++){
        bf16x8 b = *(const bf16x8*)(bufIn + lidx((eb+e2)*16+le, chunk, 24));
        acc[e2][0] = __builtin_amdgcn_mfma_f32_16x16x32_bf16(ac0, b, acc[e2][0], 0,0,0);
        acc[e2][1] = __builtin_amdgcn_mfma_f32_16x16x32_bf16(ac1, b, acc[e2][1], 0,0,0);
        ax[e2][0]  = __builtin_amdgcn_mfma_f32_16x16x32_bf16(ax0, b, ax[e2][0], 0,0,0);
        ax[e2][1]  = __builtin_amdgcn_mfma_f32_16x16x32_bf16(ax1, b, ax[e2][1], 0,0,0);
      }
    }
  }
  __syncthreads();   // all reads of u (bufIn) and bufA done
  epi8<16,true,true>(bufA,  acc, fbias + 128, q, eb, lane);  // silu(cpre+bc') -> bufA
  epi8<24,true,true>(bufIn, ax,  fbias + 256, q, eb, lane);  // silu(xpre+bx') -> bufIn 0..15
  __syncthreads();
  // c head on waves 0..3, x head on waves 4..7 — disjoint buffers, parallel
  if (wu < 4) mfma_head<16>(bufA,  whfrag + 4096, wu,   lane, c_s);
  else        mfma_head<24>(bufIn, whfrag + 6144, wu-4, lane, xx_s);
  __syncthreads();
  // combine heads
  if (t < 256){
    int e2 = t>>2; int hh = t&3;
    float g = __builtin_amdgcn_rcpf(1.0f+__expf(-(g_s[hh*65+e2]+fbias[384+hh])));
    float cwv = c_s[hh*65+e2]+cb2[hh];
    float sv = g*cwv*coordw[hh];
    float csv = xx_s[hh*65+e2]+xb2[hh];
    sv += __shfl_xor(sv,1);  sv += __shfl_xor(sv,2);
    csv += __shfl_xor(csv,1); csv += __shfl_xor(csv,2);
    if (hh==0){ s_s[e2]=sv; cs_s[e2]=csv; }
  }
  __syncthreads();
  if (t < 64){
    int ge = ebase + t;
    float rp0=rp_s[t*3],rp1=rp_s[t*3+1],rp2=rp_s[t*3+2];
    float pp0,pp1,pp2;
    if (t > 0){ pp0=rp_s[(t-1)*3]; pp1=rp_s[(t-1)*3+1]; pp2=rp_s[(t-1)*3+2]; }
    else {
      int gp = (ebase==0)? (NE-1) : (ebase-1);
      int rr=ei[gp], cc2=ei[NE+gp];
      pp0=x[rr*3]-x[cc2*3]; pp1=x[rr*3+1]-x[cc2*3+1]; pp2=x[rr*3+2]-x[cc2*3+2];
    }
    float cv0 = rp1*pp2 - rp2*pp1;
    float cv1 = rp2*pp0 - rp0*pp2;
    float cv2 = rp0*pp1 - rp1*pp0;
    float sv = s_s[t], csv = cs_s[t];
    const float inv = 1.0f/49999.0f;
    cvec[(size_t)ge*3+0] = (sv*(0.9f*rp0+0.1f*xc_s[t*3+0]) + csv*cv0)*inv;
    cvec[(size_t)ge*3+1] = (sv*(0.9f*rp1+0.1f*xc_s[t*3+1]) + csv*cv1)*inv;
    cvec[(size_t)ge*3+2] = (sv*(0.9f*rp2+0.1f*xc_s[t*3+2]) + csv*cv2)*inv;
  }
}

// ---------------- fused aggregation + out GEMM ----------------
__global__ __launch_bounds__(256) void k_aggout(
    const int* __restrict__ ei, const int* __restrict__ offs, const int* __restrict__ elist,
    const float* __restrict__ eattn, const unsigned short* __restrict__ vb,
    const float* __restrict__ cvec, const float* __restrict__ Wo, const float* __restrict__ bo,
    const float* __restrict__ asum,
    float* __restrict__ outp){
  __shared__ float wvs[4*256];
  int t = threadIdx.x; int lane = t & 63; int w = t >> 6;
  int node = blockIdx.x*4 + w;
  const int* colp = ei + NE;
  int s0 = offs[node], s1 = offs[node+1];
  float a0=0,a1=0,a2=0,a3=0,cc=0;
  int i = s0;
  for (; i+4<=s1; i+=4){
    int e0=elist[i], e1=elist[i+1], e2=elist[i+2], e3=elist[i+3];
    int c0=colp[e0], c1=colp[e1], c2=colp[e2], c3=colp[e3];
    uint2 v0 = *(const uint2*)(vb + (size_t)c0*256 + lane*4);
    uint2 v1 = *(const uint2*)(vb + (size_t)c1*256 + lane*4);
    uint2 v2 = *(const uint2*)(vb + (size_t)c2*256 + lane*4);
    uint2 v3 = *(const uint2*)(vb + (size_t)c3*256 + lane*4);
    float4 at0 = *(const float4*)(eattn + (size_t)e0*4);
    float4 at1 = *(const float4*)(eattn + (size_t)e1*4);
    float4 at2 = *(const float4*)(eattn + (size_t)e2*4);
    float4 at3 = *(const float4*)(eattn + (size_t)e3*4);
    if (lane < 3) cc += cvec[(size_t)e0*3+lane] + cvec[(size_t)e1*3+lane]
                      + cvec[(size_t)e2*3+lane] + cvec[(size_t)e3*3+lane];
    a0 += at0.x*bf2f(v0.x&0xffffu) + at1.x*bf2f(v1.x&0xffffu) + at2.x*bf2f(v2.x&0xffffu) + at3.x*bf2f(v3.x&0xffffu);
    a1 += at0.y*bf2f(v0.x>>16)     + at1.y*bf2f(v1.x>>16)     + at2.y*bf2f(v2.x>>16)     + at3.y*bf2f(v3.x>>16);
    a2 += at0.z*bf2f(v0.y&0xffffu) + at1.z*bf2f(v1.y&0xffffu) + at2.z*bf2f(v2.y&0xffffu) + at3.z*bf2f(v3.y&0xffffu);
    a3 += at0.w*bf2f(v0.y>>16)     + at1.w*bf2f(v1.y>>16)     + at2.w*bf2f(v2.y>>16)     + at3.w*bf2f(v3.y>>16);
  }
  for (; i<s1; i++){
    int e0 = elist[i];
    int c0 = colp[e0];
    uint2 v0 = *(const uint2*)(vb + (size_t)c0*256 + lane*4);
    float4 at0 = *(const float4*)(eattn + (size_t)e0*4);
    if (lane < 3) cc += cvec[(size_t)e0*3+lane];
    a0 += at0.x*bf2f(v0.x&0xffffu);
    a1 += at0.y*bf2f(v0.x>>16);
    a2 += at0.z*bf2f(v0.y&0xffffu);
    a3 += at0.w*bf2f(v0.y>>16);
  }
  {
    const float* as = asum + (size_t)node*4;
    a0 /= (as[0] + 1e-8f);
    a1 /= (as[1] + 1e-8f);
    a2 /= (as[2] + 1e-8f);
    a3 /= (as[3] + 1e-8f);
  }
  wvs[w*256 +       lane]=a0;
  wvs[w*256 +  64 + lane]=a1;
  wvs[w*256 + 128 + lane]=a2;
  wvs[w*256 + 192 + lane]=a3;
  if (lane < 3) outp[(size_t)NN*64 + (size_t)node*3 + lane] = cc;
  float o = bo[lane];
  #pragma unroll 4
  for (int k2=0;k2<256;k2++) o += wvs[w*256+k2] * Wo[k2*64+lane];
  outp[(size_t)node*64 + lane] = o;
}

extern "C" void kernel_launch(void* const* d_in, const int* in_sizes, int n_in,
                              void* d_out, int out_size, void* d_ws, size_t ws_size,
                              hipStream_t stream) {
  const float* h  = (const float*)d_in[0];
  const float* x  = (const float*)d_in[1];
  const int*   ei = (const int*)d_in[2];
  const float* Wq=(const float*)d_in[4];  const float* bq=(const float*)d_in[5];
  const float* Wk=(const float*)d_in[6];  const float* bk=(const float*)d_in[7];
  const float* Wv=(const float*)d_in[8];  const float* bv=(const float*)d_in[9];
  const float* Wo=(const float*)d_in[10]; const float* bo=(const float*)d_in[11];
  const float* pw1=(const float*)d_in[12]; const float* pb1=(const float*)d_in[13];
  const float* pw2=(const float*)d_in[14]; const float* pb2=(const float*)d_in[15];
  const float* ew1=(const float*)d_in[16]; const float* eb1=(const float*)d_in[17];
  const float* ew2=(const float*)d_in[18]; const float* eb2=(const float*)d_in[19];
  const float* eww=(const float*)d_in[20]; const float* ewb=(const float*)d_in[21];
  const float* mw1=(const float*)d_in[22]; const float* mb1=(const float*)d_in[23];
  const float* mw2=(const float*)d_in[24]; const float* mb2=(const float*)d_in[25];
  const float* gw=(const float*)d_in[26];  const float* gb=(const float*)d_in[27];
  const float* cw1=(const float*)d_in[28]; const float* cb1=(const float*)d_in[29];
  const float* cw2=(const float*)d_in[30]; const float* cb2=(const float*)d_in[31];
  const float* coordw=(const float*)d_in[32];
  const float* xw1=(const float*)d_in[33]; const float* xb1=(const float*)d_in[34];
  const float* xw2=(const float*)d_in[35]; const float* xb2=(const float*)d_in[36];

  // workspace layout (bytes), high-water = 103,829,472 (unchanged)
  char* B = (char*)d_ws;
  float* eattn = (float*)(B + 0);                        // E*4*4   = 12,800,000
  float* cvec  = (float*)(B + 12800000);                 // E*3*4   =  9,600,000
  float* stats = (float*)(B + 22400000);                 // 64 (stats[12..15] = folded ewt bias)
  float* asum  = (float*)(B + 22400064);                 // N*4*4   =    800,000
  int* counts  = (int*)(B + 23200064);                   // N*4     =    200,000  (also cursor)
  int* offs    = (int*)(B + 23400064);                   // (N+1)*4 =    200,004
  unsigned short* wfrag = (unsigned short*)(B + 23600080); // frag region 212,992 B
  int* elist   = (int*)(B + 23813088);                   // E*4     =  3,200,000
  unsigned short* qb = (unsigned short*)(B + 27013088);  // N*256*2 = 25,600,000
  unsigned short* kb = (unsigned short*)(B + 52613088);  // N*256*2 = 25,600,000
  unsigned short* vb = (unsigned short*)(B + 78213088);  // N*256*2 = 25,600,000
  unsigned short* whfrag = (unsigned short*)(B + 103813088); // 4*2048 bf16 = 16,384
  float* fbias = (float*)(wfrag + 73728);                // 388 f32 (persistent)
  // f32 fold staging in elist region (consumed before k_fill)
  float* wcomb = (float*)elist;                          // 512
  float* wgf   = wcomb + 512;                            // 512
  float* wmf   = wgf + 512;                              // 161*128 = 20,608
  float* wcf   = wmf + 20608;                            // 16,384
  float* wxf   = wcf + 16384;                            // 16,384
  unsigned short* qkvf = (unsigned short*)eattn;         // 48 tiles x 1024 shorts

  k_zero<<<977,256,0,stream>>>(stats, 250016);
  // folds
  k_wcomb<<<1,256,0,stream>>>(ew2, eww, eb2, ewb, pb2, wcomb, stats);
  k_wfoldm<<<81,256,0,stream>>>(ew2, mw1, eb2, mb1, wmf, fbias + 0);
  k_wfold<<<65,256,0,stream>>>(mw2, cw1, mb2, cb1, wcf, fbias + 128);
  k_wfold<<<65,256,0,stream>>>(mw2, xw1, mb2, xb1, wxf, fbias + 256);
  k_wfoldg<<<3,256,0,stream>>>(mw2, gw, mb2, gb, wgf, fbias + 384);
  // frag prep
  k_wprep<<<80,256,0,stream>>>(ew1, wfrag + 0,     135, 5);
  k_wprep<<<80,256,0,stream>>>(wmf, wfrag + 20480, 160, 5);
  k_wprep<<<64,256,0,stream>>>(wcf, wfrag + 40960, 128, 4);
  k_wprep<<<64,256,0,stream>>>(wxf, wfrag + 57344, 128, 4);
  k_wprepq<<<64,256,0,stream>>>(Wq, qkvf + 0);
  k_wprepq<<<64,256,0,stream>>>(Wk, qkvf + 16384);
  k_wprepq<<<64,256,0,stream>>>(Wv, qkvf + 32768);
  k_wprep4<<<8,256,0,stream>>>(wcomb, whfrag + 0);
  k_wprep4<<<8,256,0,stream>>>(wgf, whfrag + 2048);
  k_wprep4<<<8,256,0,stream>>>(cw2, whfrag + 4096);
  k_wprep4<<<8,256,0,stream>>>(xw2, whfrag + 6144);

  k_stats<<<196,256,0,stream>>>(x, stats);
  k_statsfin<<<1,64,0,stream>>>(stats);
  k_qkv2<<<782,256,0,stream>>>(h, qkvf, bq, bk, bv, qb, kb, vb);
  k_count<<<3125,256,0,stream>>>(ei,counts);
  k_scan<<<1,256,0,stream>>>(counts,offs);
  k_fill<<<3125,256,0,stream>>>(ei,counts,elist);
  k_e1<<<12500,512,0,stream>>>(h,x,ei,stats,qb,kb,wfrag,whfrag,eb1,pw1,pb1,pw2,asum,eattn);
  k_e2<<<12500,512,0,stream>>>(h,x,ei,stats,asum,eattn,wfrag,whfrag,eb1,fbias,cb2,coordw,xb2,cvec);
  k_aggout<<<12500,256,0,stream>>>(ei,offs,elist,eattn,vb,cvec,Wo,bo,asum,(float*)d_out);
}

// Round 8
// 1272.989 us; speedup vs baseline: 1.0508x; 1.0508x over previous
//
#include <hip/hip_runtime.h>
#include <hip/hip_bf16.h>

#define NN 50000
#define NE 800000

typedef __bf16 bf16x8 __attribute__((ext_vector_type(8)));
typedef float f4v __attribute__((ext_vector_type(4)));

__device__ __forceinline__ float silu_f(float v){
  return v*__builtin_amdgcn_rcpf(1.0f+__expf(-v));
}
__device__ __forceinline__ float bf2f(unsigned int u){ return __uint_as_float(u<<16); }
__device__ __forceinline__ unsigned bfr(float f){
  unsigned b = __float_as_uint(f);
  return b + 0x7fffu + ((b>>16)&1u);
}
__device__ __forceinline__ unsigned short f2bf(float f){ return (unsigned short)(bfr(f)>>16); }
__device__ __forceinline__ unsigned pk2(float a, float b){
  unsigned r;
  asm("v_cvt_pk_bf16_f32 %0, %1, %2" : "=v"(r) : "v"(a), "v"(b));
  return r;
}

union U8 { unsigned short us[8]; uint4 u4; };

__device__ __forceinline__ void pack8(unsigned short* dst, float4 a, float4 b){
  uint4 u;
  u.x = pk2(a.x,a.y); u.y = pk2(a.z,a.w);
  u.z = pk2(b.x,b.y); u.w = pk2(b.z,b.w);
  *(uint4*)dst = u;
}

// short-index of 16B chunk c of row e in a row-major swizzled activation buffer
__device__ __forceinline__ int lidx(int e, int c, int CH){
  return (e*CH + ((c & ~7) | ((c ^ e) & 7))) << 3;
}

// 8-wave GEMM: wave covers outcol-quarter q (32 cols) and edge-tile pair {eb, eb+1}
template<int KC, int CH>
__device__ __forceinline__ void gemm8(const unsigned short* act, const unsigned short* wf,
                                      int q, int eb, int lane, f4v (&acc)[2][2]){
  int le = lane & 15, quad = lane >> 4;
  #pragma unroll
  for (int kc=0;kc<KC;kc++){
    bf16x8 a0 = *(const bf16x8*)(wf + (((q*2  )*KC + kc)<<9) + lane*8);
    bf16x8 a1 = *(const bf16x8*)(wf + (((q*2+1)*KC + kc)<<9) + lane*8);
    int chunk = kc*4 + quad;
    #pragma unroll
    for (int e2=0;e2<2;e2++){
      bf16x8 b = *(const bf16x8*)(act + lidx((eb+e2)*16+le, chunk, CH));
      acc[e2][0] = __builtin_amdgcn_mfma_f32_16x16x32_bf16(a0, b, acc[e2][0], 0,0,0);
      acc[e2][1] = __builtin_amdgcn_mfma_f32_16x16x32_bf16(a1, b, acc[e2][1], 0,0,0);
    }
  }
}

// 8-wave epilogue: D regs -> row-major swizzled bf16 buffer (et range {eb,eb+1})
template<int CH, bool SILU, bool BIAS>
__device__ __forceinline__ void epi8(unsigned short* dst, const f4v (&acc)[2][2],
                                     const float* bias, int q, int eb, int lane){
  int le = lane & 15, quad = lane >> 4;
  #pragma unroll
  for (int ot=0; ot<2; ot++){
    float4 bv = make_float4(0,0,0,0);
    if (BIAS) bv = *(const float4*)(bias + q*32 + ot*16 + quad*4);
    int chunk = q*4 + ot*2 + (quad>>1);
    int soff = (quad&1)*4;
    #pragma unroll
    for (int e2=0; e2<2; e2++){
      float v0=acc[e2][ot][0], v1=acc[e2][ot][1], v2=acc[e2][ot][2], v3=acc[e2][ot][3];
      if (BIAS){ v0+=bv.x; v1+=bv.y; v2+=bv.z; v3+=bv.w; }
      if (SILU){ v0=silu_f(v0); v1=silu_f(v1); v2=silu_f(v2); v3=silu_f(v3); }
      uint2 u; u.x = pk2(v0,v1); u.y = pk2(v2,v3);
      *(uint2*)(dst + lidx((eb+e2)*16+le, chunk, CH) + soff) = u;
    }
  }
}

// head reduction as MFMA: out[h][e] = sum_k W[k][h]*act[e][k]; hu = edge-tile unit 0..3
template<int CH>
__device__ __forceinline__ void mfma_head(const unsigned short* buf, const unsigned short* whf,
                                          int hu, int lane, float* dst /*[4*65]*/){
  int le = lane & 15, quad = lane >> 4;
  f4v hacc = {0.f,0.f,0.f,0.f};
  #pragma unroll
  for (int kc=0;kc<4;kc++){
    bf16x8 a = *(const bf16x8*)(whf + (kc<<9) + lane*8);
    bf16x8 b = *(const bf16x8*)(buf + lidx(hu*16+le, kc*4+quad, CH));
    hacc = __builtin_amdgcn_mfma_f32_16x16x32_bf16(a, b, hacc, 0,0,0);
  }
  if (quad==0){
    #pragma unroll
    for (int r=0;r<4;r++) dst[r*65 + hu*16 + le] = hacc[r];
  }
}

// ---------------- zero a span ----------------
__global__ __launch_bounds__(256) void k_zero(float* __restrict__ p, int n){
  int i = blockIdx.x*256 + threadIdx.x;
  if (i < n) p[i] = 0.f;
}

// ---------------- fold ew2@eww into W' [128][4], bias' -> stats[12..15] ----------------
__global__ __launch_bounds__(256) void k_wcomb(const float* __restrict__ ew2, const float* __restrict__ eww,
                                               const float* __restrict__ eb2, const float* __restrict__ ewb,
                                               const float* __restrict__ pb2,
                                               float* __restrict__ wcomb, float* __restrict__ stats){
  int t = threadIdx.x;
  #pragma unroll
  for (int o=t;o<512;o+=256){
    int i=o>>2, hh=o&3;
    float s=0.f;
    for (int j=0;j<128;j++) s += ew2[i*128+j]*eww[j*4+hh];
    wcomb[o]=s;
  }
  if (t<4){
    float s=0.f;
    for (int j=0;j<128;j++) s += eb2[j]*eww[j*4+t];
    stats[12+t] = s + ewb[t] + pb2[t];
  }
}

// fold A(128x128)@B(128x128): dstW[i][n]=sum_j A[i][j]*B[j][n]; row 128 -> bias fold
__global__ __launch_bounds__(256) void k_wfold(const float* __restrict__ A, const float* __restrict__ Bm,
                                               const float* __restrict__ abias, const float* __restrict__ b2,
                                               float* __restrict__ dstW, float* __restrict__ dstB){
  int idx = blockIdx.x*256 + threadIdx.x;
  if (idx >= 129*128) return;
  int i = idx>>7, n = idx&127;
  if (i<128){
    float s=0.f;
    for (int j=0;j<128;j++) s += A[i*128+j]*Bm[j*128+n];
    dstW[i*128+n]=s;
  } else {
    float s=b2[n];
    for (int j=0;j<128;j++) s += abias[j]*Bm[j*128+n];
    dstB[n]=s;
  }
}

// fold ew2@mw1[0:128] -> rows 0..127; mw1 extras rows at K=144..153; rest zero.
__global__ __launch_bounds__(256) void k_wfoldm(const float* __restrict__ ew2, const float* __restrict__ mw1,
                                                const float* __restrict__ eb2, const float* __restrict__ mb1,
                                                float* __restrict__ dstW, float* __restrict__ dstB){
  int idx = blockIdx.x*256 + threadIdx.x;
  if (idx >= 161*128) return;
  int i = idx>>7, n = idx&127;
  if (i<128){
    float s=0.f;
    for (int j=0;j<128;j++) s += ew2[i*128+j]*mw1[j*128+n];
    dstW[i*128+n]=s;
  } else if (i<160){
    int r = i-144;
    dstW[i*128+n] = (r>=0 && r<10) ? mw1[(128+r)*128+n] : 0.f;
  } else {
    float s=mb1[n];
    for (int j=0;j<128;j++) s += eb2[j]*mw1[j*128+n];
    dstB[n]=s;
  }
}

// fold mw2@gw -> [128][4]; row 128 -> bg'
__global__ __launch_bounds__(256) void k_wfoldg(const float* __restrict__ mw2, const float* __restrict__ gw,
                                                const float* __restrict__ mb2, const float* __restrict__ gb,
                                                float* __restrict__ dstW, float* __restrict__ dstB){
  int idx = blockIdx.x*256 + threadIdx.x;
  if (idx >= 129*4) return;
  int i = idx>>2, hh = idx&3;
  if (i<128){
    float s=0.f;
    for (int j=0;j<128;j++) s += mw2[i*128+j]*gw[j*4+hh];
    dstW[i*4+hh]=s;
  } else {
    float s=gb[hh];
    for (int j=0;j<128;j++) s += mb2[j]*gw[j*4+hh];
    dstB[hh]=s;
  }
}

// ---------------- weight pre-pack into MFMA fragment order (bf16) ----------------
__global__ __launch_bounds__(256) void k_wprep(const float* __restrict__ src, unsigned short* __restrict__ dst,
                                               int Kreal, int KC){
  int idx = blockIdx.x*256 + threadIdx.x;
  int tot = 8*KC*512;
  if (idx >= tot) return;
  int nt  = idx/(KC*512); int rem = idx%(KC*512);
  int kc  = rem>>9;       int r2  = rem&511;
  int lq  = r2>>3;        int j   = r2&7;
  int k   = kc*32 + (lq>>4)*8 + j;
  int n   = nt*16 + (lq&15);
  float v = (k < Kreal) ? src[k*128 + n] : 0.f;
  dst[idx] = f2bf(v);
}

// qkv weight [64][256] -> 16-tile A-frag, KC=2
__global__ __launch_bounds__(256) void k_wprepq(const float* __restrict__ src, unsigned short* __restrict__ dst){
  int idx = blockIdx.x*256 + threadIdx.x;
  if (idx >= 16384) return;
  int nt  = idx>>10;  int rem = idx&1023;
  int kc  = rem>>9;   int r2  = rem&511;
  int lq  = r2>>3;    int j   = r2&7;
  int k   = kc*32 + (lq>>4)*8 + j;
  int n   = nt*16 + (lq&15);
  dst[idx] = f2bf(src[k*256 + n]);
}

// head-matrix [128][4] -> A-frag (M padded 4->16), KC=4
__global__ __launch_bounds__(256) void k_wprep4(const float* __restrict__ src, unsigned short* __restrict__ dst){
  int idx = blockIdx.x*256 + threadIdx.x;
  if (idx >= 2048) return;
  int kc = idx>>9; int r2 = idx&511; int lq = r2>>3; int j = r2&7;
  int k = kc*32 + (lq>>4)*8 + j;
  int n = lq&15;
  dst[idx] = f2bf((n<4) ? src[k*4+n] : 0.f);
}

// ---------------- stats ----------------
__global__ __launch_bounds__(256) void k_stats(const float* __restrict__ x, float* __restrict__ stats){
  int i = blockIdx.x*256 + threadIdx.x;
  float v0=0.f,v1=0.f,v2=0.f;
  if (i < NN){ v0=x[i*3+0]; v1=x[i*3+1]; v2=x[i*3+2]; }
  float vals[6] = {v0,v1,v2,v0*v0,v1*v1,v2*v2};
  __shared__ float red[256];
  for (int c=0;c<6;c++){
    red[threadIdx.x]=vals[c];
    __syncthreads();
    for (int off=128; off>0; off>>=1){
      if (threadIdx.x < off) red[threadIdx.x] += red[threadIdx.x+off];
      __syncthreads();
    }
    if (threadIdx.x==0) atomicAdd(&stats[c], red[0]);
    __syncthreads();
  }
}

__global__ __launch_bounds__(64) void k_statsfin(float* __restrict__ stats){
  int t = threadIdx.x;
  if (t < 3){
    float s = stats[t], sq = stats[3+t];
    float mean = s/(float)NN;
    float var = (sq - s*s/(float)NN)/(float)(NN-1);
    float sd = sqrtf(var);
    stats[6+t] = mean;
    stats[9+t] = 1.0f/(sd + 1e-8f);
  }
}

// ---------------- qkv via MFMA ----------------
__global__ __launch_bounds__(256) void k_qkv2(const float* __restrict__ h,
    const unsigned short* __restrict__ wqf,
    const float* __restrict__ bq, const float* __restrict__ bk, const float* __restrict__ bv,
    unsigned short* __restrict__ q, unsigned short* __restrict__ kk, unsigned short* __restrict__ v){
  __shared__ __align__(16) unsigned short hstage[64*8*8];
  int t = threadIdx.x; int lane = t & 63; int w = t >> 6;
  int wu = __builtin_amdgcn_readfirstlane(w);
  int r0 = blockIdx.x*64;
  {
    int row = r0 + lane;
    float4 a = make_float4(0,0,0,0), b2 = make_float4(0,0,0,0),
           c = make_float4(0,0,0,0), d2 = make_float4(0,0,0,0);
    if (row < NN){
      const float* hr = h + (size_t)row*64 + wu*16;
      a  = *(const float4*)(hr);    b2 = *(const float4*)(hr+4);
      c  = *(const float4*)(hr+8);  d2 = *(const float4*)(hr+12);
    }
    pack8(&hstage[lidx(lane, 2*wu,   8)], a, b2);
    pack8(&hstage[lidx(lane, 2*wu+1, 8)], c, d2);
  }
  __syncthreads();
  int le = lane & 15, quad = lane >> 4;
  #pragma unroll
  for (int ti=0; ti<12; ti++){
    int tt = ti*4 + wu;
    f4v acc[4];
    f4v z = {0.f,0.f,0.f,0.f};
    acc[0]=z; acc[1]=z; acc[2]=z; acc[3]=z;
    #pragma unroll
    for (int kc=0;kc<2;kc++){
      bf16x8 a = *(const bf16x8*)(wqf + ((tt*2 + kc)<<9) + lane*8);
      int chunk = kc*4 + quad;
      #pragma unroll
      for (int et=0;et<4;et++){
        bf16x8 b = *(const bf16x8*)(hstage + lidx(et*16+le, chunk, 8));
        acc[et] = __builtin_amdgcn_mfma_f32_16x16x32_bf16(a, b, acc[et], 0,0,0);
      }
    }
    int mat = tt>>4; int ct = tt&15;
    const float* bias = (mat==0)? bq : (mat==1)? bk : bv;
    unsigned short* outp = (mat==0)? q : (mat==1)? kk : v;
    float4 bv4 = *(const float4*)(bias + ct*16 + quad*4);
    int col = ct*16 + quad*4;
    #pragma unroll
    for (int et=0;et<4;et++){
      int row2 = r0 + et*16 + le;
      if (row2 < NN){
        float v0=acc[et][0]+bv4.x, v1=acc[et][1]+bv4.y, v2=acc[et][2]+bv4.z, v3=acc[et][3]+bv4.w;
        if (mat<2){
          uint2 u; u.x = pk2(v0,v1); u.y = pk2(v2,v3);
          *(uint2*)(outp + (size_t)row2*256 + col) = u;
        } else {
          int head = col>>6, dd = col&63;
          unsigned short* vp = outp + (size_t)row2*256 + (size_t)dd*4 + head;
          vp[0]  = f2bf(v0);
          vp[4]  = f2bf(v1);
          vp[8]  = f2bf(v2);
          vp[12] = f2bf(v3);
        }
      }
    }
  }
}

// ---------------- CSR build ----------------
__global__ __launch_bounds__(256) void k_count(const int* __restrict__ ei, int* __restrict__ counts){
  int e = blockIdx.x*256 + threadIdx.x;
  if (e < NE) atomicAdd(&counts[ei[e]], 1);
}

__global__ __launch_bounds__(256) void k_scan(int* __restrict__ counts, int* __restrict__ offs){
  __shared__ int ps[256];
  int t = threadIdx.x;
  int base = t*196;
  int s = 0;
  for (int i=0;i<196;i++){ int idx = base+i; if (idx < NN) s += counts[idx]; }
  ps[t]=s; __syncthreads();
  for (int off=1; off<256; off<<=1){
    int vv = (t>=off)? ps[t-off] : 0;
    __syncthreads();
    ps[t]+=vv;
    __syncthreads();
  }
  int run = ps[t]-s;
  for (int i=0;i<196;i++){
    int idx = base+i;
    if (idx < NN){ int c = counts[idx]; offs[idx]=run; counts[idx]=run; run+=c; }
  }
  if (t==255) offs[NN]=run;
}

__global__ __launch_bounds__(256) void k_fill(const int* __restrict__ ei, int* __restrict__ cursor, int* __restrict__ elist){
  int e = blockIdx.x*256 + threadIdx.x;
  if (e < NE){
    int r = ei[e];
    int p = atomicAdd(&cursor[r],1);
    elist[p] = e;
  }
}

// ---------------- E1: 8-wave (512 threads), 3 blocks/CU (VGPR cap 85, no spill) ----------------
// NOTE: __launch_bounds__ 2nd arg behaves as CUDA minBlocksPerMultiprocessor here:
// (512,6) produced VGPR_Count=40 = 512/(6*8/4) — i.e. blocks/CU, NOT waves/EU. Use 3.
__global__ __launch_bounds__(512, 3) void k_e1(
    const float* __restrict__ h, const float* __restrict__ x, const int* __restrict__ ei,
    const float* __restrict__ stats,
    const unsigned short* __restrict__ qb, const unsigned short* __restrict__ kb,
    const unsigned short* __restrict__ wfrag, const unsigned short* __restrict__ whfrag,
    const float* __restrict__ eb1,
    const float* __restrict__ pw1, const float* __restrict__ pb1,
    const float* __restrict__ pw2,
    float* __restrict__ asum, float* __restrict__ eattn){
  __shared__ __align__(16) unsigned short bufIn[64*24*8];
  __shared__ float logit_s[256];
  __shared__ float ewt2_s[4*65];
  __shared__ float pos_s[4*65];
  __shared__ float rd_s[64], xnr_s[192], xnc_s[192];
  __shared__ int row_s[64], col_s[64];
  int t = threadIdx.x; int lane = t & 63; int w = t >> 6;
  int wu = __builtin_amdgcn_readfirstlane(w);
  int q = wu & 3, eb = (wu>>2)*2;
  int ebase = blockIdx.x * 64;

  for (int i=t;i<260;i+=512) pos_s[i]=0.f;
  if (t < 64){
    int ge = ebase + t;
    int r = ei[ge], c = ei[NE+ge];
    row_s[t]=r; col_s[t]=c;
    float xr0=x[r*3],xr1=x[r*3+1],xr2=x[r*3+2];
    float xc0=x[c*3],xc1=x[c*3+1],xc2=x[c*3+2];
    float rp0=xr0-xc0, rp1=xr1-xc1, rp2=xr2-xc2;
    rd_s[t]=rp0*rp0+rp1*rp1+rp2*rp2;
    float m0=stats[6],m1=stats[7],m2=stats[8],s0=stats[9],s1=stats[10],s2=stats[11];
    xnr_s[t*3+0]=(xr0-m0)*s0; xnr_s[t*3+1]=(xr1-m1)*s1; xnr_s[t*3+2]=(xr2-m2)*s2;
    xnc_s[t*3+0]=(xc0-m0)*s0; xnc_s[t*3+1]=(xc1-m1)*s1; xnc_s[t*3+2]=(xc2-m2)*s2;
  }
  __syncthreads();

  // q.k dots: 8 edges per wave
  for (int ii=0; ii<8; ii++){
    int e = wu*8+ii;
    int r = row_s[e], c = col_s[e];
    uint2 qu = *(const uint2*)(qb + (size_t)r*256 + lane*4);
    uint2 ku = *(const uint2*)(kb + (size_t)c*256 + lane*4);
    float d = bf2f(qu.x&0xffffu)*bf2f(ku.x&0xffffu)
            + bf2f(qu.x>>16)   *bf2f(ku.x>>16)
            + bf2f(qu.y&0xffffu)*bf2f(ku.y&0xffffu)
            + bf2f(qu.y>>16)   *bf2f(ku.y>>16);
    d += __shfl_xor(d,1,16); d += __shfl_xor(d,2,16);
    d += __shfl_xor(d,4,16); d += __shfl_xor(d,8,16);
    if ((lane&15)==0) logit_s[e*4 + (lane>>4)] = d*0.125f;
  }
  // pos_enc partials: 8 j-slices of 8
  {
    int jb = wu*8;
    float rd = rd_s[lane];
    float p0=0,p1=0,p2=0,p3=0;
    for (int j=jb; j<jb+8; j++){
      float hp = rd*pw1[j] + pb1[j];
      float hs = silu_f(hp);
      const float4 w4 = *(const float4*)(pw2 + j*4);
      p0+=hs*w4.x; p1+=hs*w4.y; p2+=hs*w4.z; p3+=hs*w4.w;
    }
    atomicAdd(&pos_s[0*65+lane],p0);
    atomicAdd(&pos_s[1*65+lane],p1);
    atomicAdd(&pos_s[2*65+lane],p2);
    atomicAdd(&pos_s[3*65+lane],p3);
  }
  // stage: waves 0..3 h[row] slices, waves 4..7 h[col] slices
  if (wu < 4){
    const float* hr = h + (size_t)row_s[lane]*64 + wu*16;
    pack8(&bufIn[lidx(lane, 2*wu,   24)], *(const float4*)(hr),   *(const float4*)(hr+4));
    pack8(&bufIn[lidx(lane, 2*wu+1, 24)], *(const float4*)(hr+8), *(const float4*)(hr+12));
  } else {
    int s = wu-4;
    const float* hc = h + (size_t)col_s[lane]*64 + s*16;
    pack8(&bufIn[lidx(lane, 8+2*s, 24)], *(const float4*)(hc),   *(const float4*)(hc+4));
    pack8(&bufIn[lidx(lane, 9+2*s, 24)], *(const float4*)(hc+8), *(const float4*)(hc+12));
  }
  if (t < 64){
    pack8(&bufIn[lidx(t,16,24)],
          make_float4(rd_s[t], xnr_s[t*3+0], xnr_s[t*3+1], xnr_s[t*3+2]),
          make_float4(xnc_s[t*3+0], xnc_s[t*3+1], xnc_s[t*3+2], 0.f));
  }
  {
    uint4 z4 = make_uint4(0,0,0,0);
    int e = t&63, j = t>>6;
    if (j < 3) *(uint4*)&bufIn[lidx(e, 17+j, 24)] = z4;
  }
  __syncthreads();
  f4v acc[2][2];
  f4v z = {0.f,0.f,0.f,0.f};
  acc[0][0]=z; acc[0][1]=z; acc[1][0]=z; acc[1][1]=z;
  gemm8<5,24>(bufIn, wfrag + 0, q, eb, lane, acc);
  __syncthreads();            // all waves done reading bufIn before overwrite
  epi8<24,true,true>(bufIn, acc, eb1, q, eb, lane);
  __syncthreads();
  if (wu < 4) mfma_head<24>(bufIn, whfrag + 0, wu, lane, ewt2_s);
  __syncthreads();
  if (t < 256){
    int e2 = t>>2, hh = t&3;
    float lg = logit_s[t] + stats[12+hh] + ewt2_s[hh*65+e2] + pos_s[hh*65+e2];
    float ex = __expf(lg);
    eattn[(size_t)ebase*4 + t] = ex;
    atomicAdd(&asum[row_s[e2]*4 + hh], ex);
  }
}

// ---------------- E2: 8-wave (512 threads), folded, ping-pong, 3 blocks/CU ----------------
__global__ __launch_bounds__(512, 3) void k_e2(
    const float* __restrict__ h, const float* __restrict__ x, const int* __restrict__ ei,
    const float* __restrict__ stats,
    const float* __restrict__ asum, const float* __restrict__ eattn,
    const unsigned short* __restrict__ wfrag, const unsigned short* __restrict__ whfrag,
    const float* __restrict__ eb1, const float* __restrict__ fbias, // [0]=bm' [128]=bc' [256]=bx' [384..387]=bg'
    const float* __restrict__ cb2, const float* __restrict__ coordw,
    const float* __restrict__ xb2,
    float* __restrict__ cvec){
  __shared__ __align__(16) unsigned short bufIn[64*24*8];
  __shared__ __align__(16) unsigned short bufA [64*16*8];
  __shared__ float g_s[4*65], c_s[4*65], xx_s[4*65];
  __shared__ float s_s[64], cs_s[64];
  __shared__ float rp_s[192], rd_s[64], xnr_s[192], xnc_s[192], xc_s[192];
  __shared__ int row_s[64], col_s[64];
  int t = threadIdx.x; int lane = t & 63; int w = t >> 6;
  int wu = __builtin_amdgcn_readfirstlane(w);
  int q = wu & 3, eb = (wu>>2)*2;
  int ebase = blockIdx.x * 64;

  float am = 0.f;
  if (t < 64){
    int ge = ebase + t;
    int r = ei[ge], c = ei[NE+ge];
    row_s[t]=r; col_s[t]=c;
    // prefetch attn/asum early: latency hides under geometry + staging
    float4 at = *(const float4*)(eattn + (size_t)ge*4);
    const float* as4 = asum + (size_t)r*4;
    float a0=as4[0],a1=as4[1],a2=as4[2],a3=as4[3];
    float xr0=x[r*3],xr1=x[r*3+1],xr2=x[r*3+2];
    float xc0=x[c*3],xc1=x[c*3+1],xc2=x[c*3+2];
    float rp0=xr0-xc0, rp1=xr1-xc1, rp2=xr2-xc2;
    rp_s[t*3+0]=rp0; rp_s[t*3+1]=rp1; rp_s[t*3+2]=rp2;
    rd_s[t]=rp0*rp0+rp1*rp1+rp2*rp2;
    xc_s[t*3+0]=xc0; xc_s[t*3+1]=xc1; xc_s[t*3+2]=xc2;
    float m0=stats[6],m1=stats[7],m2=stats[8],s0=stats[9],s1=stats[10],s2=stats[11];
    xnr_s[t*3+0]=(xr0-m0)*s0; xnr_s[t*3+1]=(xr1-m1)*s1; xnr_s[t*3+2]=(xr2-m2)*s2;
    xnc_s[t*3+0]=(xc0-m0)*s0; xnc_s[t*3+1]=(xc1-m1)*s1; xnc_s[t*3+2]=(xc2-m2)*s2;
    am = 0.25f*( at.x/(a0+1e-8f) + at.y/(a1+1e-8f)
               + at.z/(a2+1e-8f) + at.w/(a3+1e-8f) );
  }
  __syncthreads();
  // stage h[row] (waves 0..3) / h[col] (waves 4..7)
  if (wu < 4){
    const float* hr = h + (size_t)row_s[lane]*64 + wu*16;
    pack8(&bufIn[lidx(lane, 2*wu,   24)], *(const float4*)(hr),   *(const float4*)(hr+4));
    pack8(&bufIn[lidx(lane, 2*wu+1, 24)], *(const float4*)(hr+8), *(const float4*)(hr+12));
  } else {
    int s = wu-4;
    const float* hc = h + (size_t)col_s[lane]*64 + s*16;
    pack8(&bufIn[lidx(lane, 8+2*s, 24)], *(const float4*)(hc),   *(const float4*)(hc+4));
    pack8(&bufIn[lidx(lane, 9+2*s, 24)], *(const float4*)(hc+8), *(const float4*)(hc+12));
  }
  // extras: chunk16 = edge_attr extras; chunk17 zeros; chunks 18,19 = m_in extras
  if (t < 64){
    pack8(&bufIn[lidx(t,16,24)],
          make_float4(rd_s[t], xnr_s[t*3+0], xnr_s[t*3+1], xnr_s[t*3+2]),
          make_float4(xnc_s[t*3+0], xnc_s[t*3+1], xnc_s[t*3+2], 0.f));
    *(uint4*)&bufIn[lidx(t,17,24)] = make_uint4(0,0,0,0);
    pack8(&bufIn[lidx(t,18,24)],
          make_float4(am, rp_s[t*3+0], rp_s[t*3+1], rp_s[t*3+2]),
          make_float4(xnr_s[t*3+0], xnr_s[t*3+1], xnr_s[t*3+2], xnc_s[t*3+0]));
    pack8(&bufIn[lidx(t,19,24)],
          make_float4(xnc_s[t*3+1], xnc_s[t*3+2], 0.f, 0.f),
          make_float4(0.f,0.f,0.f,0.f));
  }
  __syncthreads();
  f4v acc[2][2], ax[2][2];
  f4v z = {0.f,0.f,0.f,0.f};
  // G1: ew1 (KC=5, zeros beyond K=135) -> u1 = silu(+eb1) -> bufA
  acc[0][0]=z; acc[0][1]=z; acc[1][0]=z; acc[1][1]=z;
  gemm8<5,24>(bufIn, wfrag + 0, q, eb, lane, acc);
  epi8<16,true,true>(bufA, acc, eb1, q, eb, lane);
  __syncthreads();
  // G3': mw1' — kc 0..3 from bufA (u1), kc 4 from bufIn chunks 16..19 (extras)
  acc[0][0]=z; acc[0][1]=z; acc[1][0]=z; acc[1][1]=z;
  {
    const unsigned short* wf = wfrag + 20480;
    int le = lane&15, quad = lane>>4;
    #pragma unroll
    for (int kc=0;kc<5;kc++){
      bf16x8 a0 = *(const bf16x8*)(wf + (((q*2  )*5 + kc)<<9) + lane*8);
      bf16x8 a1 = *(const bf16x8*)(wf + (((q*2+1)*5 + kc)<<9) + lane*8);
      int chunk = kc*4 + quad;
      #pragma unroll
      for (int e2=0;e2<2;e2++){
        bf16x8 b = (kc<4) ? *(const bf16x8*)(bufA  + lidx((eb+e2)*16+le, chunk, 16))
                          : *(const bf16x8*)(bufIn + lidx((eb+e2)*16+le, chunk, 24));
        acc[e2][0] = __builtin_amdgcn_mfma_f32_16x16x32_bf16(a0, b, acc[e2][0], 0,0,0);
        acc[e2][1] = __builtin_amdgcn_mfma_f32_16x16x32_bf16(a1, b, acc[e2][1], 0,0,0);
      }
    }
  }
  // u -> bufIn 0..15 (safe: G3' readers touch only bufA + bufIn chunks 16..19)
  epi8<24,true,true>(bufIn, acc, fbias + 0, q, eb, lane);
  __syncthreads();
  // gates head (waves 0..3, read-only on u) + G5/G6 folded cw1'/xw1' (all waves)
  if (wu < 4) mfma_head<24>(bufIn, whfrag + 2048, wu, lane, g_s);
  acc[0][0]=z; acc[0][1]=z; acc[1][0]=z; acc[1][1]=z;
  ax[0][0]=z; ax[0][1]=z; ax[1][0]=z; ax[1][1]=z;
  {
    const unsigned short* wfc = wfrag + 40960;
    const unsigned short* wfx = wfrag + 57344;
    int le = lane&15, quad = lane>>4;
    #pragma unroll
    for (int kc=0;kc<4;kc++){
      bf16x8 ac0 = *(const bf16x8*)(wfc + (((q*2  )*4 + kc)<<9) + lane*8);
      bf16x8 ac1 = *(const bf16x8*)(wfc + (((q*2+1)*4 + kc)<<9) + lane*8);
      bf16x8 ax0 = *(const bf16x8*)(wfx + (((q*2  )*4 + kc)<<9) + lane*8);
      bf16x8 ax1 = *(const bf16x8*)(wfx + (((q*2+1)*4 + kc)<<9) + lane*8);
      int chunk = kc*4 + quad;
      #pragma unroll
      for (int e2=0;e2<2;e2++){
        bf16x8 b = *(const bf16x8*)(bufIn + lidx((eb+e2)*16+le, chunk, 24));
        acc[e2][0] = __builtin_amdgcn_mfma_f32_16x16x32_bf16(ac0, b, acc[e2][0], 0,0,0);
        acc[e2][1] = __builtin_amdgcn_mfma_f32_16x16x32_bf16(ac1, b, acc[e2][1], 0,0,0);
        ax[e2][0]  = __builtin_amdgcn_mfma_f32_16x16x32_bf16(ax0, b, ax[e2][0], 0,0,0);
        ax[e2][1]  = __builtin_amdgcn_mfma_f32_16x16x32_bf16(ax1, b, ax[e2][1], 0,0,0);
      }
    }
  }
  __syncthreads();   // all reads of u (bufIn) and bufA done
  epi8<16,true,true>(bufA,  acc, fbias + 128, q, eb, lane);  // silu(cpre+bc') -> bufA
  epi8<24,true,true>(bufIn, ax,  fbias + 256, q, eb, lane);  // silu(xpre+bx') -> bufIn 0..15
  __syncthreads();
  // c head on waves 0..3, x head on waves 4..7 — disjoint buffers, parallel
  if (wu < 4) mfma_head<16>(bufA,  whfrag + 4096, wu,   lane, c_s);
  else        mfma_head<24>(bufIn, whfrag + 6144, wu-4, lane, xx_s);
  __syncthreads();
  // combine heads
  if (t < 256){
    int e2 = t>>2; int hh = t&3;
    float g = __builtin_amdgcn_rcpf(1.0f+__expf(-(g_s[hh*65+e2]+fbias[384+hh])));
    float cwv = c_s[hh*65+e2]+cb2[hh];
    float sv = g*cwv*coordw[hh];
    float csv = xx_s[hh*65+e2]+xb2[hh];
    sv += __shfl_xor(sv,1);  sv += __shfl_xor(sv,2);
    csv += __shfl_xor(csv,1); csv += __shfl_xor(csv,2);
    if (hh==0){ s_s[e2]=sv; cs_s[e2]=csv; }
  }
  __syncthreads();
  if (t < 64){
    int ge = ebase + t;
    float rp0=rp_s[t*3],rp1=rp_s[t*3+1],rp2=rp_s[t*3+2];
    float pp0,pp1,pp2;
    if (t > 0){ pp0=rp_s[(t-1)*3]; pp1=rp_s[(t-1)*3+1]; pp2=rp_s[(t-1)*3+2]; }
    else {
      int gp = (ebase==0)? (NE-1) : (ebase-1);
      int rr=ei[gp], cc2=ei[NE+gp];
      pp0=x[rr*3]-x[cc2*3]; pp1=x[rr*3+1]-x[cc2*3+1]; pp2=x[rr*3+2]-x[cc2*3+2];
    }
    float cv0 = rp1*pp2 - rp2*pp1;
    float cv1 = rp2*pp0 - rp0*pp2;
    float cv2 = rp0*pp1 - rp1*pp0;
    float sv = s_s[t], csv = cs_s[t];
    const float inv = 1.0f/49999.0f;
    cvec[(size_t)ge*3+0] = (sv*(0.9f*rp0+0.1f*xc_s[t*3+0]) + csv*cv0)*inv;
    cvec[(size_t)ge*3+1] = (sv*(0.9f*rp1+0.1f*xc_s[t*3+1]) + csv*cv1)*inv;
    cvec[(size_t)ge*3+2] = (sv*(0.9f*rp2+0.1f*xc_s[t*3+2]) + csv*cv2)*inv;
  }
}

// ---------------- fused aggregation + out GEMM ----------------
__global__ __launch_bounds__(256) void k_aggout(
    const int* __restrict__ ei, const int* __restrict__ offs, const int* __restrict__ elist,
    const float* __restrict__ eattn, const unsigned short* __restrict__ vb,
    const float* __restrict__ cvec, const float* __restrict__ Wo, const float* __restrict__ bo,
    const float* __restrict__ asum,
    float* __restrict__ outp){
  __shared__ float wvs[4*256];
  int t = threadIdx.x; int lane = t & 63; int w = t >> 6;
  int node = blockIdx.x*4 + w;
  const int* colp = ei + NE;
  int s0 = offs[node], s1 = offs[node+1];
  float a0=0,a1=0,a2=0,a3=0,cc=0;
  int i = s0;
  for (; i+4<=s1; i+=4){
    int e0=elist[i], e1=elist[i+1], e2=elist[i+2], e3=elist[i+3];
    int c0=colp[e0], c1=colp[e1], c2=colp[e2], c3=colp[e3];
    uint2 v0 = *(const uint2*)(vb + (size_t)c0*256 + lane*4);
    uint2 v1 = *(const uint2*)(vb + (size_t)c1*256 + lane*4);
    uint2 v2 = *(const uint2*)(vb + (size_t)c2*256 + lane*4);
    uint2 v3 = *(const uint2*)(vb + (size_t)c3*256 + lane*4);
    float4 at0 = *(const float4*)(eattn + (size_t)e0*4);
    float4 at1 = *(const float4*)(eattn + (size_t)e1*4);
    float4 at2 = *(const float4*)(eattn + (size_t)e2*4);
    float4 at3 = *(const float4*)(eattn + (size_t)e3*4);
    if (lane < 3) cc += cvec[(size_t)e0*3+lane] + cvec[(size_t)e1*3+lane]
                      + cvec[(size_t)e2*3+lane] + cvec[(size_t)e3*3+lane];
    a0 += at0.x*bf2f(v0.x&0xffffu) + at1.x*bf2f(v1.x&0xffffu) + at2.x*bf2f(v2.x&0xffffu) + at3.x*bf2f(v3.x&0xffffu);
    a1 += at0.y*bf2f(v0.x>>16)     + at1.y*bf2f(v1.x>>16)     + at2.y*bf2f(v2.x>>16)     + at3.y*bf2f(v3.x>>16);
    a2 += at0.z*bf2f(v0.y&0xffffu) + at1.z*bf2f(v1.y&0xffffu) + at2.z*bf2f(v2.y&0xffffu) + at3.z*bf2f(v3.y&0xffffu);
    a3 += at0.w*bf2f(v0.y>>16)     + at1.w*bf2f(v1.y>>16)     + at2.w*bf2f(v2.y>>16)     + at3.w*bf2f(v3.y>>16);
  }
  for (; i<s1; i++){
    int e0 = elist[i];
    int c0 = colp[e0];
    uint2 v0 = *(const uint2*)(vb + (size_t)c0*256 + lane*4);
    float4 at0 = *(const float4*)(eattn + (size_t)e0*4);
    if (lane < 3) cc += cvec[(size_t)e0*3+lane];
    a0 += at0.x*bf2f(v0.x&0xffffu);
    a1 += at0.y*bf2f(v0.x>>16);
    a2 += at0.z*bf2f(v0.y&0xffffu);
    a3 += at0.w*bf2f(v0.y>>16);
  }
  {
    const float* as = asum + (size_t)node*4;
    a0 /= (as[0] + 1e-8f);
    a1 /= (as[1] + 1e-8f);
    a2 /= (as[2] + 1e-8f);
    a3 /= (as[3] + 1e-8f);
  }
  wvs[w*256 +       lane]=a0;
  wvs[w*256 +  64 + lane]=a1;
  wvs[w*256 + 128 + lane]=a2;
  wvs[w*256 + 192 + lane]=a3;
  if (lane < 3) outp[(size_t)NN*64 + (size_t)node*3 + lane] = cc;
  float o = bo[lane];
  #pragma unroll 4
  for (int k2=0;k2<256;k2++) o += wvs[w*256+k2] * Wo[k2*64+lane];
  outp[(size_t)node*64 + lane] = o;
}

extern "C" void kernel_launch(void* const* d_in, const int* in_sizes, int n_in,
                              void* d_out, int out_size, void* d_ws, size_t ws_size,
                              hipStream_t stream) {
  const float* h  = (const float*)d_in[0];
  const float* x  = (const float*)d_in[1];
  const int*   ei = (const int*)d_in[2];
  const float* Wq=(const float*)d_in[4];  const float* bq=(const float*)d_in[5];
  const float* Wk=(const float*)d_in[6];  const float* bk=(const float*)d_in[7];
  const float* Wv=(const float*)d_in[8];  const float* bv=(const float*)d_in[9];
  const float* Wo=(const float*)d_in[10]; const float* bo=(const float*)d_in[11];
  const float* pw1=(const float*)d_in[12]; const float* pb1=(const float*)d_in[13];
  const float* pw2=(const float*)d_in[14]; const float* pb2=(const float*)d_in[15];
  const float* ew1=(const float*)d_in[16]; const float* eb1=(const float*)d_in[17];
  const float* ew2=(const float*)d_in[18]; const float* eb2=(const float*)d_in[19];
  const float* eww=(const float*)d_in[20]; const float* ewb=(const float*)d_in[21];
  const float* mw1=(const float*)d_in[22]; const float* mb1=(const float*)d_in[23];
  const float* mw2=(const float*)d_in[24]; const float* mb2=(const float*)d_in[25];
  const float* gw=(const float*)d_in[26];  const float* gb=(const float*)d_in[27];
  const float* cw1=(const float*)d_in[28]; const float* cb1=(const float*)d_in[29];
  const float* cw2=(const float*)d_in[30]; const float* cb2=(const float*)d_in[31];
  const float* coordw=(const float*)d_in[32];
  const float* xw1=(const float*)d_in[33]; const float* xb1=(const float*)d_in[34];
  const float* xw2=(const float*)d_in[35]; const float* xb2=(const float*)d_in[36];

  // workspace layout (bytes), high-water = 103,829,472 (unchanged)
  char* B = (char*)d_ws;
  float* eattn = (float*)(B + 0);                        // E*4*4   = 12,800,000
  float* cvec  = (float*)(B + 12800000);                 // E*3*4   =  9,600,000
  float* stats = (float*)(B + 22400000);                 // 64 (stats[12..15] = folded ewt bias)
  float* asum  = (float*)(B + 22400064);                 // N*4*4   =    800,000
  int* counts  = (int*)(B + 23200064);                   // N*4     =    200,000  (also cursor)
  int* offs    = (int*)(B + 23400064);                   // (N+1)*4 =    200,004
  unsigned short* wfrag = (unsigned short*)(B + 23600080); // frag region 212,992 B
  int* elist   = (int*)(B + 23813088);                   // E*4     =  3,200,000
  unsigned short* qb = (unsigned short*)(B + 27013088);  // N*256*2 = 25,600,000
  unsigned short* kb = (unsigned short*)(B + 52613088);  // N*256*2 = 25,600,000
  unsigned short* vb = (unsigned short*)(B + 78213088);  // N*256*2 = 25,600,000
  unsigned short* whfrag = (unsigned short*)(B + 103813088); // 4*2048 bf16 = 16,384
  float* fbias = (float*)(wfrag + 73728);                // 388 f32 (persistent)
  // f32 fold staging in elist region (consumed before k_fill)
  float* wcomb = (float*)elist;                          // 512
  float* wgf   = wcomb + 512;                            // 512
  float* wmf   = wgf + 512;                              // 161*128 = 20,608
  float* wcf   = wmf + 20608;                            // 16,384
  float* wxf   = wcf + 16384;                            // 16,384
  unsigned short* qkvf = (unsigned short*)eattn;         // 48 tiles x 1024 shorts

  k_zero<<<977,256,0,stream>>>(stats, 250016);
  // folds
  k_wcomb<<<1,256,0,stream>>>(ew2, eww, eb2, ewb, pb2, wcomb, stats);
  k_wfoldm<<<81,256,0,stream>>>(ew2, mw1, eb2, mb1, wmf, fbias + 0);
  k_wfold<<<65,256,0,stream>>>(mw2, cw1, mb2, cb1, wcf, fbias + 128);
  k_wfold<<<65,256,0,stream>>>(mw2, xw1, mb2, xb1, wxf, fbias + 256);
  k_wfoldg<<<3,256,0,stream>>>(mw2, gw, mb2, gb, wgf, fbias + 384);
  // frag prep
  k_wprep<<<80,256,0,stream>>>(ew1, wfrag + 0,     135, 5);
  k_wprep<<<80,256,0,stream>>>(wmf, wfrag + 20480, 160, 5);
  k_wprep<<<64,256,0,stream>>>(wcf, wfrag + 40960, 128, 4);
  k_wprep<<<64,256,0,stream>>>(wxf, wfrag + 57344, 128, 4);
  k_wprepq<<<64,256,0,stream>>>(Wq, qkvf + 0);
  k_wprepq<<<64,256,0,stream>>>(Wk, qkvf + 16384);
  k_wprepq<<<64,256,0,stream>>>(Wv, qkvf + 32768);
  k_wprep4<<<8,256,0,stream>>>(wcomb, whfrag + 0);
  k_wprep4<<<8,256,0,stream>>>(wgf, whfrag + 2048);
  k_wprep4<<<8,256,0,stream>>>(cw2, whfrag + 4096);
  k_wprep4<<<8,256,0,stream>>>(xw2, whfrag + 6144);

  k_stats<<<196,256,0,stream>>>(x, stats);
  k_statsfin<<<1,64,0,stream>>>(stats);
  k_qkv2<<<782,256,0,stream>>>(h, qkvf, bq, bk, bv, qb, kb, vb);
  k_count<<<3125,256,0,stream>>>(ei,counts);
  k_scan<<<1,256,0,stream>>>(counts,offs);
  k_fill<<<3125,256,0,stream>>>(ei,counts,elist);
  k_e1<<<12500,512,0,stream>>>(h,x,ei,stats,qb,kb,wfrag,whfrag,eb1,pw1,pb1,pw2,asum,eattn);
  k_e2<<<12500,512,0,stream>>>(h,x,ei,stats,asum,eattn,wfrag,whfrag,eb1,fbias,cb2,coordw,xb2,cvec);
  k_aggout<<<12500,256,0,stream>>>(ei,offs,elist,eattn,vb,cvec,Wo,bo,asum,(float*)d_out);
}

// Round 9
// 1187.252 us; speedup vs baseline: 1.1266x; 1.0722x over previous
//
#include <hip/hip_runtime.h>
#include <hip/hip_bf16.h>

#define NN 50000
#define NE 800000

typedef __bf16 bf16x8 __attribute__((ext_vector_type(8)));
typedef float f4v __attribute__((ext_vector_type(4)));

__device__ __forceinline__ float silu_f(float v){
  return v*__builtin_amdgcn_rcpf(1.0f+__expf(-v));
}
__device__ __forceinline__ float bf2f(unsigned int u){ return __uint_as_float(u<<16); }
__device__ __forceinline__ unsigned bfr(float f){
  unsigned b = __float_as_uint(f);
  return b + 0x7fffu + ((b>>16)&1u);
}
__device__ __forceinline__ unsigned short f2bf(float f){ return (unsigned short)(bfr(f)>>16); }
__device__ __forceinline__ unsigned pk2(float a, float b){
  unsigned r;
  asm("v_cvt_pk_bf16_f32 %0, %1, %2" : "=v"(r) : "v"(a), "v"(b));
  return r;
}

union U8 { unsigned short us[8]; uint4 u4; };

__device__ __forceinline__ void pack8(unsigned short* dst, float4 a, float4 b){
  uint4 u;
  u.x = pk2(a.x,a.y); u.y = pk2(a.z,a.w);
  u.z = pk2(b.x,b.y); u.w = pk2(b.z,b.w);
  *(uint4*)dst = u;
}

// short-index of 16B chunk c of row e in a row-major swizzled activation buffer
__device__ __forceinline__ int lidx(int e, int c, int CH){
  return (e*CH + ((c & ~7) | ((c ^ e) & 7))) << 3;
}

// 8-wave GEMM: wave covers outcol-quarter q (32 cols) and edge-tile pair {eb, eb+1}
template<int KC, int CH>
__device__ __forceinline__ void gemm8(const unsigned short* act, const unsigned short* wf,
                                      int q, int eb, int lane, f4v (&acc)[2][2]){
  int le = lane & 15, quad = lane >> 4;
  #pragma unroll
  for (int kc=0;kc<KC;kc++){
    bf16x8 a0 = *(const bf16x8*)(wf + (((q*2  )*KC + kc)<<9) + lane*8);
    bf16x8 a1 = *(const bf16x8*)(wf + (((q*2+1)*KC + kc)<<9) + lane*8);
    int chunk = kc*4 + quad;
    #pragma unroll
    for (int e2=0;e2<2;e2++){
      bf16x8 b = *(const bf16x8*)(act + lidx((eb+e2)*16+le, chunk, CH));
      acc[e2][0] = __builtin_amdgcn_mfma_f32_16x16x32_bf16(a0, b, acc[e2][0], 0,0,0);
      acc[e2][1] = __builtin_amdgcn_mfma_f32_16x16x32_bf16(a1, b, acc[e2][1], 0,0,0);
    }
  }
}

// 8-wave epilogue: D regs -> row-major swizzled bf16 buffer (et range {eb,eb+1})
template<int CH, bool SILU, bool BIAS>
__device__ __forceinline__ void epi8(unsigned short* dst, const f4v (&acc)[2][2],
                                     const float* bias, int q, int eb, int lane){
  int le = lane & 15, quad = lane >> 4;
  #pragma unroll
  for (int ot=0; ot<2; ot++){
    float4 bv = make_float4(0,0,0,0);
    if (BIAS) bv = *(const float4*)(bias + q*32 + ot*16 + quad*4);
    int chunk = q*4 + ot*2 + (quad>>1);
    int soff = (quad&1)*4;
    #pragma unroll
    for (int e2=0; e2<2; e2++){
      float v0=acc[e2][ot][0], v1=acc[e2][ot][1], v2=acc[e2][ot][2], v3=acc[e2][ot][3];
      if (BIAS){ v0+=bv.x; v1+=bv.y; v2+=bv.z; v3+=bv.w; }
      if (SILU){ v0=silu_f(v0); v1=silu_f(v1); v2=silu_f(v2); v3=silu_f(v3); }
      uint2 u; u.x = pk2(v0,v1); u.y = pk2(v2,v3);
      *(uint2*)(dst + lidx((eb+e2)*16+le, chunk, CH) + soff) = u;
    }
  }
}

// head reduction as MFMA: out[h][e] = sum_k W[k][h]*act[e][k]; hu = edge-tile unit 0..3
template<int CH>
__device__ __forceinline__ void mfma_head(const unsigned short* buf, const unsigned short* whf,
                                          int hu, int lane, float* dst /*[4*65]*/){
  int le = lane & 15, quad = lane >> 4;
  f4v hacc = {0.f,0.f,0.f,0.f};
  #pragma unroll
  for (int kc=0;kc<4;kc++){
    bf16x8 a = *(const bf16x8*)(whf + (kc<<9) + lane*8);
    bf16x8 b = *(const bf16x8*)(buf + lidx(hu*16+le, kc*4+quad, CH));
    hacc = __builtin_amdgcn_mfma_f32_16x16x32_bf16(a, b, hacc, 0,0,0);
  }
  if (quad==0){
    #pragma unroll
    for (int r=0;r<4;r++) dst[r*65 + hu*16 + le] = hacc[r];
  }
}

// ---------------- zero a span ----------------
__global__ __launch_bounds__(256) void k_zero(float* __restrict__ p, int n){
  int i = blockIdx.x*256 + threadIdx.x;
  if (i < n) p[i] = 0.f;
}

// ---------------- fold ew2@eww into W' [128][4], bias' -> stats[12..15] ----------------
__global__ __launch_bounds__(256) void k_wcomb(const float* __restrict__ ew2, const float* __restrict__ eww,
                                               const float* __restrict__ eb2, const float* __restrict__ ewb,
                                               const float* __restrict__ pb2,
                                               float* __restrict__ wcomb, float* __restrict__ stats){
  int t = threadIdx.x;
  #pragma unroll
  for (int o=t;o<512;o+=256){
    int i=o>>2, hh=o&3;
    float s=0.f;
    for (int j=0;j<128;j++) s += ew2[i*128+j]*eww[j*4+hh];
    wcomb[o]=s;
  }
  if (t<4){
    float s=0.f;
    for (int j=0;j<128;j++) s += eb2[j]*eww[j*4+t];
    stats[12+t] = s + ewb[t] + pb2[t];
  }
}

// fold A(128x128)@B(128x128): dstW[i][n]=sum_j A[i][j]*B[j][n]; row 128 -> bias fold
__global__ __launch_bounds__(256) void k_wfold(const float* __restrict__ A, const float* __restrict__ Bm,
                                               const float* __restrict__ abias, const float* __restrict__ b2,
                                               float* __restrict__ dstW, float* __restrict__ dstB){
  int idx = blockIdx.x*256 + threadIdx.x;
  if (idx >= 129*128) return;
  int i = idx>>7, n = idx&127;
  if (i<128){
    float s=0.f;
    for (int j=0;j<128;j++) s += A[i*128+j]*Bm[j*128+n];
    dstW[i*128+n]=s;
  } else {
    float s=b2[n];
    for (int j=0;j<128;j++) s += abias[j]*Bm[j*128+n];
    dstB[n]=s;
  }
}

// fold ew2@mw1[0:128] -> rows 0..127; mw1 extras rows at K=144..153; rest zero.
__global__ __launch_bounds__(256) void k_wfoldm(const float* __restrict__ ew2, const float* __restrict__ mw1,
                                                const float* __restrict__ eb2, const float* __restrict__ mb1,
                                                float* __restrict__ dstW, float* __restrict__ dstB){
  int idx = blockIdx.x*256 + threadIdx.x;
  if (idx >= 161*128) return;
  int i = idx>>7, n = idx&127;
  if (i<128){
    float s=0.f;
    for (int j=0;j<128;j++) s += ew2[i*128+j]*mw1[j*128+n];
    dstW[i*128+n]=s;
  } else if (i<160){
    int r = i-144;
    dstW[i*128+n] = (r>=0 && r<10) ? mw1[(128+r)*128+n] : 0.f;
  } else {
    float s=mb1[n];
    for (int j=0;j<128;j++) s += eb2[j]*mw1[j*128+n];
    dstB[n]=s;
  }
}

// fold mw2@gw -> [128][4]; row 128 -> bg'
__global__ __launch_bounds__(256) void k_wfoldg(const float* __restrict__ mw2, const float* __restrict__ gw,
                                                const float* __restrict__ mb2, const float* __restrict__ gb,
                                                float* __restrict__ dstW, float* __restrict__ dstB){
  int idx = blockIdx.x*256 + threadIdx.x;
  if (idx >= 129*4) return;
  int i = idx>>2, hh = idx&3;
  if (i<128){
    float s=0.f;
    for (int j=0;j<128;j++) s += mw2[i*128+j]*gw[j*4+hh];
    dstW[i*4+hh]=s;
  } else {
    float s=gb[hh];
    for (int j=0;j<128;j++) s += mb2[j]*gw[j*4+hh];
    dstB[hh]=s;
  }
}

// ---------------- weight pre-pack into MFMA fragment order (bf16) ----------------
__global__ __launch_bounds__(256) void k_wprep(const float* __restrict__ src, unsigned short* __restrict__ dst,
                                               int Kreal, int KC){
  int idx = blockIdx.x*256 + threadIdx.x;
  int tot = 8*KC*512;
  if (idx >= tot) return;
  int nt  = idx/(KC*512); int rem = idx%(KC*512);
  int kc  = rem>>9;       int r2  = rem&511;
  int lq  = r2>>3;        int j   = r2&7;
  int k   = kc*32 + (lq>>4)*8 + j;
  int n   = nt*16 + (lq&15);
  float v = (k < Kreal) ? src[k*128 + n] : 0.f;
  dst[idx] = f2bf(v);
}

// qkv weight [64][256] -> 16-tile A-frag, KC=2
__global__ __launch_bounds__(256) void k_wprepq(const float* __restrict__ src, unsigned short* __restrict__ dst){
  int idx = blockIdx.x*256 + threadIdx.x;
  if (idx >= 16384) return;
  int nt  = idx>>10;  int rem = idx&1023;
  int kc  = rem>>9;   int r2  = rem&511;
  int lq  = r2>>3;    int j   = r2&7;
  int k   = kc*32 + (lq>>4)*8 + j;
  int n   = nt*16 + (lq&15);
  dst[idx] = f2bf(src[k*256 + n]);
}

// Wo [256][64] -> 4-tile A-frag, KC=8 (16,384 shorts)
__global__ __launch_bounds__(256) void k_wprepo(const float* __restrict__ src, unsigned short* __restrict__ dst){
  int idx = blockIdx.x*256 + threadIdx.x;
  if (idx >= 16384) return;
  int nt  = idx>>12;  int rem = idx&4095;
  int kc  = rem>>9;   int r2  = rem&511;
  int lq  = r2>>3;    int j   = r2&7;
  int k   = kc*32 + (lq>>4)*8 + j;   // < 256
  int n   = nt*16 + (lq&15);         // < 64
  dst[idx] = f2bf(src[k*64 + n]);
}

// head-matrix [128][4] -> A-frag (M padded 4->16), KC=4
__global__ __launch_bounds__(256) void k_wprep4(const float* __restrict__ src, unsigned short* __restrict__ dst){
  int idx = blockIdx.x*256 + threadIdx.x;
  if (idx >= 2048) return;
  int kc = idx>>9; int r2 = idx&511; int lq = r2>>3; int j = r2&7;
  int k = kc*32 + (lq>>4)*8 + j;
  int n = lq&15;
  dst[idx] = f2bf((n<4) ? src[k*4+n] : 0.f);
}

// ---------------- stats ----------------
__global__ __launch_bounds__(256) void k_stats(const float* __restrict__ x, float* __restrict__ stats){
  int i = blockIdx.x*256 + threadIdx.x;
  float v0=0.f,v1=0.f,v2=0.f;
  if (i < NN){ v0=x[i*3+0]; v1=x[i*3+1]; v2=x[i*3+2]; }
  float vals[6] = {v0,v1,v2,v0*v0,v1*v1,v2*v2};
  __shared__ float red[256];
  for (int c=0;c<6;c++){
    red[threadIdx.x]=vals[c];
    __syncthreads();
    for (int off=128; off>0; off>>=1){
      if (threadIdx.x < off) red[threadIdx.x] += red[threadIdx.x+off];
      __syncthreads();
    }
    if (threadIdx.x==0) atomicAdd(&stats[c], red[0]);
    __syncthreads();
  }
}

__global__ __launch_bounds__(64) void k_statsfin(float* __restrict__ stats){
  int t = threadIdx.x;
  if (t < 3){
    float s = stats[t], sq = stats[3+t];
    float mean = s/(float)NN;
    float var = (sq - s*s/(float)NN)/(float)(NN-1);
    float sd = sqrtf(var);
    stats[6+t] = mean;
    stats[9+t] = 1.0f/(sd + 1e-8f);
  }
}

// ---------------- qkv via MFMA ----------------
__global__ __launch_bounds__(256) void k_qkv2(const float* __restrict__ h,
    const unsigned short* __restrict__ wqf,
    const float* __restrict__ bq, const float* __restrict__ bk, const float* __restrict__ bv,
    unsigned short* __restrict__ q, unsigned short* __restrict__ kk, unsigned short* __restrict__ v){
  __shared__ __align__(16) unsigned short hstage[64*8*8];
  int t = threadIdx.x; int lane = t & 63; int w = t >> 6;
  int wu = __builtin_amdgcn_readfirstlane(w);
  int r0 = blockIdx.x*64;
  {
    int row = r0 + lane;
    float4 a = make_float4(0,0,0,0), b2 = make_float4(0,0,0,0),
           c = make_float4(0,0,0,0), d2 = make_float4(0,0,0,0);
    if (row < NN){
      const float* hr = h + (size_t)row*64 + wu*16;
      a  = *(const float4*)(hr);    b2 = *(const float4*)(hr+4);
      c  = *(const float4*)(hr+8);  d2 = *(const float4*)(hr+12);
    }
    pack8(&hstage[lidx(lane, 2*wu,   8)], a, b2);
    pack8(&hstage[lidx(lane, 2*wu+1, 8)], c, d2);
  }
  __syncthreads();
  int le = lane & 15, quad = lane >> 4;
  #pragma unroll
  for (int ti=0; ti<12; ti++){
    int tt = ti*4 + wu;
    f4v acc[4];
    f4v z = {0.f,0.f,0.f,0.f};
    acc[0]=z; acc[1]=z; acc[2]=z; acc[3]=z;
    #pragma unroll
    for (int kc=0;kc<2;kc++){
      bf16x8 a = *(const bf16x8*)(wqf + ((tt*2 + kc)<<9) + lane*8);
      int chunk = kc*4 + quad;
      #pragma unroll
      for (int et=0;et<4;et++){
        bf16x8 b = *(const bf16x8*)(hstage + lidx(et*16+le, chunk, 8));
        acc[et] = __builtin_amdgcn_mfma_f32_16x16x32_bf16(a, b, acc[et], 0,0,0);
      }
    }
    int mat = tt>>4; int ct = tt&15;
    const float* bias = (mat==0)? bq : (mat==1)? bk : bv;
    unsigned short* outp = (mat==0)? q : (mat==1)? kk : v;
    float4 bv4 = *(const float4*)(bias + ct*16 + quad*4);
    int col = ct*16 + quad*4;
    #pragma unroll
    for (int et=0;et<4;et++){
      int row2 = r0 + et*16 + le;
      if (row2 < NN){
        float v0=acc[et][0]+bv4.x, v1=acc[et][1]+bv4.y, v2=acc[et][2]+bv4.z, v3=acc[et][3]+bv4.w;
        if (mat<2){
          uint2 u; u.x = pk2(v0,v1); u.y = pk2(v2,v3);
          *(uint2*)(outp + (size_t)row2*256 + col) = u;
        } else {
          int head = col>>6, dd = col&63;
          unsigned short* vp = outp + (size_t)row2*256 + (size_t)dd*4 + head;
          vp[0]  = f2bf(v0);
          vp[4]  = f2bf(v1);
          vp[8]  = f2bf(v2);
          vp[12] = f2bf(v3);
        }
      }
    }
  }
}

// ---------------- CSR build ----------------
__global__ __launch_bounds__(256) void k_count(const int* __restrict__ ei, int* __restrict__ counts){
  int e = blockIdx.x*256 + threadIdx.x;
  if (e < NE) atomicAdd(&counts[ei[e]], 1);
}

__global__ __launch_bounds__(256) void k_scan(int* __restrict__ counts, int* __restrict__ offs){
  __shared__ int ps[256];
  int t = threadIdx.x;
  int base = t*196;
  int s = 0;
  for (int i=0;i<196;i++){ int idx = base+i; if (idx < NN) s += counts[idx]; }
  ps[t]=s; __syncthreads();
  for (int off=1; off<256; off<<=1){
    int vv = (t>=off)? ps[t-off] : 0;
    __syncthreads();
    ps[t]+=vv;
    __syncthreads();
  }
  int run = ps[t]-s;
  for (int i=0;i<196;i++){
    int idx = base+i;
    if (idx < NN){ int c = counts[idx]; offs[idx]=run; counts[idx]=run; run+=c; }
  }
  if (t==255) offs[NN]=run;
}

__global__ __launch_bounds__(256) void k_fill(const int* __restrict__ ei, int* __restrict__ cursor, int* __restrict__ elist){
  int e = blockIdx.x*256 + threadIdx.x;
  if (e < NE){
    int r = ei[e];
    int p = atomicAdd(&cursor[r],1);
    elist[p] = e;
  }
}

// ---------------- E1: 8-wave (512 threads), 4 blocks/CU (VGPR cap 64) ----------------
// __launch_bounds__ 2nd arg = min BLOCKS per CU on this toolchain (verified R7: (512,6)->VGPR 40).
__global__ __launch_bounds__(512, 4) void k_e1(
    const float* __restrict__ h, const float* __restrict__ x, const int* __restrict__ ei,
    const float* __restrict__ stats,
    const unsigned short* __restrict__ qb, const unsigned short* __restrict__ kb,
    const unsigned short* __restrict__ wfrag, const unsigned short* __restrict__ whfrag,
    const float* __restrict__ eb1,
    const float* __restrict__ pw1, const float* __restrict__ pb1,
    const float* __restrict__ pw2,
    float* __restrict__ asum, float* __restrict__ eattn){
  __shared__ __align__(16) unsigned short bufIn[64*24*8];
  __shared__ float logit_s[256];
  __shared__ float ewt2_s[4*65];
  __shared__ float pos_s[4*65];
  __shared__ float rd_s[64], xnr_s[192], xnc_s[192];
  __shared__ int row_s[64], col_s[64];
  int t = threadIdx.x; int lane = t & 63; int w = t >> 6;
  int wu = __builtin_amdgcn_readfirstlane(w);
  int q = wu & 3, eb = (wu>>2)*2;
  int ebase = blockIdx.x * 64;

  for (int i=t;i<260;i+=512) pos_s[i]=0.f;
  if (t < 64){
    int ge = ebase + t;
    int r = ei[ge], c = ei[NE+ge];
    row_s[t]=r; col_s[t]=c;
    float xr0=x[r*3],xr1=x[r*3+1],xr2=x[r*3+2];
    float xc0=x[c*3],xc1=x[c*3+1],xc2=x[c*3+2];
    float rp0=xr0-xc0, rp1=xr1-xc1, rp2=xr2-xc2;
    rd_s[t]=rp0*rp0+rp1*rp1+rp2*rp2;
    float m0=stats[6],m1=stats[7],m2=stats[8],s0=stats[9],s1=stats[10],s2=stats[11];
    xnr_s[t*3+0]=(xr0-m0)*s0; xnr_s[t*3+1]=(xr1-m1)*s1; xnr_s[t*3+2]=(xr2-m2)*s2;
    xnc_s[t*3+0]=(xc0-m0)*s0; xnc_s[t*3+1]=(xc1-m1)*s1; xnc_s[t*3+2]=(xc2-m2)*s2;
  }
  __syncthreads();

  // q.k dots: 8 edges per wave
  for (int ii=0; ii<8; ii++){
    int e = wu*8+ii;
    int r = row_s[e], c = col_s[e];
    uint2 qu = *(const uint2*)(qb + (size_t)r*256 + lane*4);
    uint2 ku = *(const uint2*)(kb + (size_t)c*256 + lane*4);
    float d = bf2f(qu.x&0xffffu)*bf2f(ku.x&0xffffu)
            + bf2f(qu.x>>16)   *bf2f(ku.x>>16)
            + bf2f(qu.y&0xffffu)*bf2f(ku.y&0xffffu)
            + bf2f(qu.y>>16)   *bf2f(ku.y>>16);
    d += __shfl_xor(d,1,16); d += __shfl_xor(d,2,16);
    d += __shfl_xor(d,4,16); d += __shfl_xor(d,8,16);
    if ((lane&15)==0) logit_s[e*4 + (lane>>4)] = d*0.125f;
  }
  // pos_enc partials: 8 j-slices of 8
  {
    int jb = wu*8;
    float rd = rd_s[lane];
    float p0=0,p1=0,p2=0,p3=0;
    for (int j=jb; j<jb+8; j++){
      float hp = rd*pw1[j] + pb1[j];
      float hs = silu_f(hp);
      const float4 w4 = *(const float4*)(pw2 + j*4);
      p0+=hs*w4.x; p1+=hs*w4.y; p2+=hs*w4.z; p3+=hs*w4.w;
    }
    atomicAdd(&pos_s[0*65+lane],p0);
    atomicAdd(&pos_s[1*65+lane],p1);
    atomicAdd(&pos_s[2*65+lane],p2);
    atomicAdd(&pos_s[3*65+lane],p3);
  }
  // stage: waves 0..3 h[row] slices, waves 4..7 h[col] slices
  if (wu < 4){
    const float* hr = h + (size_t)row_s[lane]*64 + wu*16;
    pack8(&bufIn[lidx(lane, 2*wu,   24)], *(const float4*)(hr),   *(const float4*)(hr+4));
    pack8(&bufIn[lidx(lane, 2*wu+1, 24)], *(const float4*)(hr+8), *(const float4*)(hr+12));
  } else {
    int s = wu-4;
    const float* hc = h + (size_t)col_s[lane]*64 + s*16;
    pack8(&bufIn[lidx(lane, 8+2*s, 24)], *(const float4*)(hc),   *(const float4*)(hc+4));
    pack8(&bufIn[lidx(lane, 9+2*s, 24)], *(const float4*)(hc+8), *(const float4*)(hc+12));
  }
  if (t < 64){
    pack8(&bufIn[lidx(t,16,24)],
          make_float4(rd_s[t], xnr_s[t*3+0], xnr_s[t*3+1], xnr_s[t*3+2]),
          make_float4(xnc_s[t*3+0], xnc_s[t*3+1], xnc_s[t*3+2], 0.f));
  }
  {
    uint4 z4 = make_uint4(0,0,0,0);
    int e = t&63, j = t>>6;
    if (j < 3) *(uint4*)&bufIn[lidx(e, 17+j, 24)] = z4;
  }
  __syncthreads();
  f4v acc[2][2];
  f4v z = {0.f,0.f,0.f,0.f};
  acc[0][0]=z; acc[0][1]=z; acc[1][0]=z; acc[1][1]=z;
  gemm8<5,24>(bufIn, wfrag + 0, q, eb, lane, acc);
  __syncthreads();            // all waves done reading bufIn before overwrite
  epi8<24,true,true>(bufIn, acc, eb1, q, eb, lane);
  __syncthreads();
  if (wu < 4) mfma_head<24>(bufIn, whfrag + 0, wu, lane, ewt2_s);
  __syncthreads();
  if (t < 256){
    int e2 = t>>2, hh = t&3;
    float lg = logit_s[t] + stats[12+hh] + ewt2_s[hh*65+e2] + pos_s[hh*65+e2];
    float ex = __expf(lg);
    eattn[(size_t)ebase*4 + t] = ex;
    atomicAdd(&asum[row_s[e2]*4 + hh], ex);
  }
}

// ---------------- E2: 8-wave (512 threads), folded, ping-pong, 3 blocks/CU ----------------
__global__ __launch_bounds__(512, 3) void k_e2(
    const float* __restrict__ h, const float* __restrict__ x, const int* __restrict__ ei,
    const float* __restrict__ stats,
    const float* __restrict__ asum, const float* __restrict__ eattn,
    const unsigned short* __restrict__ wfrag, const unsigned short* __restrict__ whfrag,
    const float* __restrict__ eb1, const float* __restrict__ fbias, // [0]=bm' [128]=bc' [256]=bx' [384..387]=bg'
    const float* __restrict__ cb2, const float* __restrict__ coordw,
    const float* __restrict__ xb2,
    float* __restrict__ cvec){
  __shared__ __align__(16) unsigned short bufIn[64*24*8];
  __shared__ __align__(16) unsigned short bufA [64*16*8];
  __shared__ float g_s[4*65], c_s[4*65], xx_s[4*65];
  __shared__ float s_s[64], cs_s[64];
  __shared__ float rp_s[192], rd_s[64], xnr_s[192], xnc_s[192], xc_s[192];
  __shared__ int row_s[64], col_s[64];
  int t = threadIdx.x; int lane = t & 63; int w = t >> 6;
  int wu = __builtin_amdgcn_readfirstlane(w);
  int q = wu & 3, eb = (wu>>2)*2;
  int ebase = blockIdx.x * 64;

  float am = 0.f;
  if (t < 64){
    int ge = ebase + t;
    int r = ei[ge], c = ei[NE+ge];
    row_s[t]=r; col_s[t]=c;
    // prefetch attn/asum early: latency hides under geometry + staging
    float4 at = *(const float4*)(eattn + (size_t)ge*4);
    const float* as4 = asum + (size_t)r*4;
    float a0=as4[0],a1=as4[1],a2=as4[2],a3=as4[3];
    float xr0=x[r*3],xr1=x[r*3+1],xr2=x[r*3+2];
    float xc0=x[c*3],xc1=x[c*3+1],xc2=x[c*3+2];
    float rp0=xr0-xc0, rp1=xr1-xc1, rp2=xr2-xc2;
    rp_s[t*3+0]=rp0; rp_s[t*3+1]=rp1; rp_s[t*3+2]=rp2;
    rd_s[t]=rp0*rp0+rp1*rp1+rp2*rp2;
    xc_s[t*3+0]=xc0; xc_s[t*3+1]=xc1; xc_s[t*3+2]=xc2;
    float m0=stats[6],m1=stats[7],m2=stats[8],s0=stats[9],s1=stats[10],s2=stats[11];
    xnr_s[t*3+0]=(xr0-m0)*s0; xnr_s[t*3+1]=(xr1-m1)*s1; xnr_s[t*3+2]=(xr2-m2)*s2;
    xnc_s[t*3+0]=(xc0-m0)*s0; xnc_s[t*3+1]=(xc1-m1)*s1; xnc_s[t*3+2]=(xc2-m2)*s2;
    am = 0.25f*( at.x/(a0+1e-8f) + at.y/(a1+1e-8f)
               + at.z/(a2+1e-8f) + at.w/(a3+1e-8f) );
  }
  __syncthreads();
  // stage h[row] (waves 0..3) / h[col] (waves 4..7)
  if (wu < 4){
    const float* hr = h + (size_t)row_s[lane]*64 + wu*16;
    pack8(&bufIn[lidx(lane, 2*wu,   24)], *(const float4*)(hr),   *(const float4*)(hr+4));
    pack8(&bufIn[lidx(lane, 2*wu+1, 24)], *(const float4*)(hr+8), *(const float4*)(hr+12));
  } else {
    int s = wu-4;
    const float* hc = h + (size_t)col_s[lane]*64 + s*16;
    pack8(&bufIn[lidx(lane, 8+2*s, 24)], *(const float4*)(hc),   *(const float4*)(hc+4));
    pack8(&bufIn[lidx(lane, 9+2*s, 24)], *(const float4*)(hc+8), *(const float4*)(hc+12));
  }
  // extras: chunk16 = edge_attr extras; chunk17 zeros; chunks 18,19 = m_in extras
  if (t < 64){
    pack8(&bufIn[lidx(t,16,24)],
          make_float4(rd_s[t], xnr_s[t*3+0], xnr_s[t*3+1], xnr_s[t*3+2]),
          make_float4(xnc_s[t*3+0], xnc_s[t*3+1], xnc_s[t*3+2], 0.f));
    *(uint4*)&bufIn[lidx(t,17,24)] = make_uint4(0,0,0,0);
    pack8(&bufIn[lidx(t,18,24)],
          make_float4(am, rp_s[t*3+0], rp_s[t*3+1], rp_s[t*3+2]),
          make_float4(xnr_s[t*3+0], xnr_s[t*3+1], xnr_s[t*3+2], xnc_s[t*3+0]));
    pack8(&bufIn[lidx(t,19,24)],
          make_float4(xnc_s[t*3+1], xnc_s[t*3+2], 0.f, 0.f),
          make_float4(0.f,0.f,0.f,0.f));
  }
  __syncthreads();
  f4v acc[2][2], ax[2][2];
  f4v z = {0.f,0.f,0.f,0.f};
  // G1: ew1 (KC=5, zeros beyond K=135) -> u1 = silu(+eb1) -> bufA
  acc[0][0]=z; acc[0][1]=z; acc[1][0]=z; acc[1][1]=z;
  gemm8<5,24>(bufIn, wfrag + 0, q, eb, lane, acc);
  epi8<16,true,true>(bufA, acc, eb1, q, eb, lane);
  __syncthreads();
  // G3': mw1' — kc 0..3 from bufA (u1), kc 4 from bufIn chunks 16..19 (extras)
  acc[0][0]=z; acc[0][1]=z; acc[1][0]=z; acc[1][1]=z;
  {
    const unsigned short* wf = wfrag + 20480;
    int le = lane&15, quad = lane>>4;
    #pragma unroll
    for (int kc=0;kc<5;kc++){
      bf16x8 a0 = *(const bf16x8*)(wf + (((q*2  )*5 + kc)<<9) + lane*8);
      bf16x8 a1 = *(const bf16x8*)(wf + (((q*2+1)*5 + kc)<<9) + lane*8);
      int chunk = kc*4 + quad;
      #pragma unroll
      for (int e2=0;e2<2;e2++){
        bf16x8 b = (kc<4) ? *(const bf16x8*)(bufA  + lidx((eb+e2)*16+le, chunk, 16))
                          : *(const bf16x8*)(bufIn + lidx((eb+e2)*16+le, chunk, 24));
        acc[e2][0] = __builtin_amdgcn_mfma_f32_16x16x32_bf16(a0, b, acc[e2][0], 0,0,0);
        acc[e2][1] = __builtin_amdgcn_mfma_f32_16x16x32_bf16(a1, b, acc[e2][1], 0,0,0);
      }
    }
  }
  // u -> bufIn 0..15 (safe: G3' readers touch only bufA + bufIn chunks 16..19)
  epi8<24,true,true>(bufIn, acc, fbias + 0, q, eb, lane);
  __syncthreads();
  // gates head (waves 0..3, read-only on u) + G5/G6 folded cw1'/xw1' (all waves)
  if (wu < 4) mfma_head<24>(bufIn, whfrag + 2048, wu, lane, g_s);
  acc[0][0]=z; acc[0][1]=z; acc[1][0]=z; acc[1][1]=z;
  ax[0][0]=z; ax[0][1]=z; ax[1][0]=z; ax[1][1]=z;
  {
    const unsigned short* wfc = wfrag + 40960;
    const unsigned short* wfx = wfrag + 57344;
    int le = lane&15, quad = lane>>4;
    #pragma unroll
    for (int kc=0;kc<4;kc++){
      bf16x8 ac0 = *(const bf16x8*)(wfc + (((q*2  )*4 + kc)<<9) + lane*8);
      bf16x8 ac1 = *(const bf16x8*)(wfc + (((q*2+1)*4 + kc)<<9) + lane*8);
      bf16x8 ax0 = *(const bf16x8*)(wfx + (((q*2  )*4 + kc)<<9) + lane*8);
      bf16x8 ax1 = *(const bf16x8*)(wfx + (((q*2+1)*4 + kc)<<9) + lane*8);
      int chunk = kc*4 + quad;
      #pragma unroll
      for (int e2=0;e2<2;e2++){
        bf16x8 b = *(const bf16x8*)(bufIn + lidx((eb+e2)*16+le, chunk, 24));
        acc[e2][0] = __builtin_amdgcn_mfma_f32_16x16x32_bf16(ac0, b, acc[e2][0], 0,0,0);
        acc[e2][1] = __builtin_amdgcn_mfma_f32_16x16x32_bf16(ac1, b, acc[e2][1], 0,0,0);
        ax[e2][0]  = __builtin_amdgcn_mfma_f32_16x16x32_bf16(ax0, b, ax[e2][0], 0,0,0);
        ax[e2][1]  = __builtin_amdgcn_mfma_f32_16x16x32_bf16(ax1, b, ax[e2][1], 0,0,0);
      }
    }
  }
  __syncthreads();   // all reads of u (bufIn) and bufA done
  epi8<16,true,true>(bufA,  acc, fbias + 128, q, eb, lane);  // silu(cpre+bc') -> bufA
  epi8<24,true,true>(bufIn, ax,  fbias + 256, q, eb, lane);  // silu(xpre+bx') -> bufIn 0..15
  __syncthreads();
  // c head on waves 0..3, x head on waves 4..7 — disjoint buffers, parallel
  if (wu < 4) mfma_head<16>(bufA,  whfrag + 4096, wu,   lane, c_s);
  else        mfma_head<24>(bufIn, whfrag + 6144, wu-4, lane, xx_s);
  __syncthreads();
  // combine heads
  if (t < 256){
    int e2 = t>>2; int hh = t&3;
    float g = __builtin_amdgcn_rcpf(1.0f+__expf(-(g_s[hh*65+e2]+fbias[384+hh])));
    float cwv = c_s[hh*65+e2]+cb2[hh];
    float sv = g*cwv*coordw[hh];
    float csv = xx_s[hh*65+e2]+xb2[hh];
    sv += __shfl_xor(sv,1);  sv += __shfl_xor(sv,2);
    csv += __shfl_xor(csv,1); csv += __shfl_xor(csv,2);
    if (hh==0){ s_s[e2]=sv; cs_s[e2]=csv; }
  }
  __syncthreads();
  if (t < 64){
    int ge = ebase + t;
    float rp0=rp_s[t*3],rp1=rp_s[t*3+1],rp2=rp_s[t*3+2];
    float pp0,pp1,pp2;
    if (t > 0){ pp0=rp_s[(t-1)*3]; pp1=rp_s[(t-1)*3+1]; pp2=rp_s[(t-1)*3+2]; }
    else {
      int gp = (ebase==0)? (NE-1) : (ebase-1);
      int rr=ei[gp], cc2=ei[NE+gp];
      pp0=x[rr*3]-x[cc2*3]; pp1=x[rr*3+1]-x[cc2*3+1]; pp2=x[rr*3+2]-x[cc2*3+2];
    }
    float cv0 = rp1*pp2 - rp2*pp1;
    float cv1 = rp2*pp0 - rp0*pp2;
    float cv2 = rp0*pp1 - rp1*pp0;
    float sv = s_s[t], csv = cs_s[t];
    const float inv = 1.0f/49999.0f;
    cvec[(size_t)ge*3+0] = (sv*(0.9f*rp0+0.1f*xc_s[t*3+0]) + csv*cv0)*inv;
    cvec[(size_t)ge*3+1] = (sv*(0.9f*rp1+0.1f*xc_s[t*3+1]) + csv*cv1)*inv;
    cvec[(size_t)ge*3+2] = (sv*(0.9f*rp2+0.1f*xc_s[t*3+2]) + csv*cv2)*inv;
  }
}

// ---------------- aggregation only: wv (bf16) + coord output ----------------
__global__ __launch_bounds__(256) void k_agg(
    const int* __restrict__ ei, const int* __restrict__ offs, const int* __restrict__ elist,
    const float* __restrict__ eattn, const unsigned short* __restrict__ vb,
    const float* __restrict__ cvec, const float* __restrict__ asum,
    unsigned short* __restrict__ wv, float* __restrict__ outp){
  int t = threadIdx.x; int lane = t & 63; int w = t >> 6;
  int node = blockIdx.x*4 + w;
  const int* colp = ei + NE;
  int s0 = offs[node], s1 = offs[node+1];
  float a0=0,a1=0,a2=0,a3=0,cc=0;
  int i = s0;
  for (; i+4<=s1; i+=4){
    int e0=elist[i], e1=elist[i+1], e2=elist[i+2], e3=elist[i+3];
    int c0=colp[e0], c1=colp[e1], c2=colp[e2], c3=colp[e3];
    uint2 v0 = *(const uint2*)(vb + (size_t)c0*256 + lane*4);
    uint2 v1 = *(const uint2*)(vb + (size_t)c1*256 + lane*4);
    uint2 v2 = *(const uint2*)(vb + (size_t)c2*256 + lane*4);
    uint2 v3 = *(const uint2*)(vb + (size_t)c3*256 + lane*4);
    float4 at0 = *(const float4*)(eattn + (size_t)e0*4);
    float4 at1 = *(const float4*)(eattn + (size_t)e1*4);
    float4 at2 = *(const float4*)(eattn + (size_t)e2*4);
    float4 at3 = *(const float4*)(eattn + (size_t)e3*4);
    if (lane < 3) cc += cvec[(size_t)e0*3+lane] + cvec[(size_t)e1*3+lane]
                      + cvec[(size_t)e2*3+lane] + cvec[(size_t)e3*3+lane];
    a0 += at0.x*bf2f(v0.x&0xffffu) + at1.x*bf2f(v1.x&0xffffu) + at2.x*bf2f(v2.x&0xffffu) + at3.x*bf2f(v3.x&0xffffu);
    a1 += at0.y*bf2f(v0.x>>16)     + at1.y*bf2f(v1.x>>16)     + at2.y*bf2f(v2.x>>16)     + at3.y*bf2f(v3.x>>16);
    a2 += at0.z*bf2f(v0.y&0xffffu) + at1.z*bf2f(v1.y&0xffffu) + at2.z*bf2f(v2.y&0xffffu) + at3.z*bf2f(v3.y&0xffffu);
    a3 += at0.w*bf2f(v0.y>>16)     + at1.w*bf2f(v1.y>>16)     + at2.w*bf2f(v2.y>>16)     + at3.w*bf2f(v3.y>>16);
  }
  for (; i<s1; i++){
    int e0 = elist[i];
    int c0 = colp[e0];
    uint2 v0 = *(const uint2*)(vb + (size_t)c0*256 + lane*4);
    float4 at0 = *(const float4*)(eattn + (size_t)e0*4);
    if (lane < 3) cc += cvec[(size_t)e0*3+lane];
    a0 += at0.x*bf2f(v0.x&0xffffu);
    a1 += at0.y*bf2f(v0.x>>16);
    a2 += at0.z*bf2f(v0.y&0xffffu);
    a3 += at0.w*bf2f(v0.y>>16);
  }
  {
    const float* as = asum + (size_t)node*4;
    a0 /= (as[0] + 1e-8f);
    a1 /= (as[1] + 1e-8f);
    a2 /= (as[2] + 1e-8f);
    a3 /= (as[3] + 1e-8f);
  }
  // wv flat index = head*64 + d (matches Wo row order); d = lane
  unsigned short* wp = wv + (size_t)node*256 + lane;
  wp[0]   = f2bf(a0);
  wp[64]  = f2bf(a1);
  wp[128] = f2bf(a2);
  wp[192] = f2bf(a3);
  if (lane < 3) outp[(size_t)NN*64 + (size_t)node*3 + lane] = cc;
}

// ---------------- out GEMM via MFMA: [NN x 256] @ Wo[256 x 64] ----------------
__global__ __launch_bounds__(256) void k_out(
    const unsigned short* __restrict__ wv, const unsigned short* __restrict__ wof,
    const float* __restrict__ bo, float* __restrict__ outp){
  __shared__ __align__(16) unsigned short hstage[64*32*8];   // 64 rows x 256 cols bf16, CH=32
  int t = threadIdx.x; int lane = t & 63; int w = t >> 6;
  int wu = __builtin_amdgcn_readfirstlane(w);
  int r0 = blockIdx.x*64;
  {
    int row = r0 + lane;
    #pragma unroll
    for (int k=0;k<8;k++){
      uint4 u = make_uint4(0,0,0,0);
      if (row < NN) u = *(const uint4*)(wv + (size_t)row*256 + (size_t)(wu*8+k)*8);
      *(uint4*)&hstage[lidx(lane, wu*8+k, 32)] = u;
    }
  }
  __syncthreads();
  int le = lane & 15, quad = lane >> 4;
  f4v acc[4];
  f4v z = {0.f,0.f,0.f,0.f};
  acc[0]=z; acc[1]=z; acc[2]=z; acc[3]=z;
  #pragma unroll
  for (int kc=0;kc<8;kc++){
    bf16x8 a = *(const bf16x8*)(wof + ((wu*8 + kc)<<9) + lane*8);
    int chunk = kc*4 + quad;
    #pragma unroll
    for (int et=0;et<4;et++){
      bf16x8 b = *(const bf16x8*)(hstage + lidx(et*16+le, chunk, 32));
      acc[et] = __builtin_amdgcn_mfma_f32_16x16x32_bf16(a, b, acc[et], 0,0,0);
    }
  }
  int col = wu*16 + quad*4;
  float4 bv4 = *(const float4*)(bo + col);
  #pragma unroll
  for (int et=0;et<4;et++){
    int row2 = r0 + et*16 + le;
    if (row2 < NN){
      float4 o = make_float4(acc[et][0]+bv4.x, acc[et][1]+bv4.y, acc[et][2]+bv4.z, acc[et][3]+bv4.w);
      *(float4*)(outp + (size_t)row2*64 + col) = o;
    }
  }
}

extern "C" void kernel_launch(void* const* d_in, const int* in_sizes, int n_in,
                              void* d_out, int out_size, void* d_ws, size_t ws_size,
                              hipStream_t stream) {
  const float* h  = (const float*)d_in[0];
  const float* x  = (const float*)d_in[1];
  const int*   ei = (const int*)d_in[2];
  const float* Wq=(const float*)d_in[4];  const float* bq=(const float*)d_in[5];
  const float* Wk=(const float*)d_in[6];  const float* bk=(const float*)d_in[7];
  const float* Wv=(const float*)d_in[8];  const float* bv=(const float*)d_in[9];
  const float* Wo=(const float*)d_in[10]; const float* bo=(const float*)d_in[11];
  const float* pw1=(const float*)d_in[12]; const float* pb1=(const float*)d_in[13];
  const float* pw2=(const float*)d_in[14]; const float* pb2=(const float*)d_in[15];
  const float* ew1=(const float*)d_in[16]; const float* eb1=(const float*)d_in[17];
  const float* ew2=(const float*)d_in[18]; const float* eb2=(const float*)d_in[19];
  const float* eww=(const float*)d_in[20]; const float* ewb=(const float*)d_in[21];
  const float* mw1=(const float*)d_in[22]; const float* mb1=(const float*)d_in[23];
  const float* mw2=(const float*)d_in[24]; const float* mb2=(const float*)d_in[25];
  const float* gw=(const float*)d_in[26];  const float* gb=(const float*)d_in[27];
  const float* cw1=(const float*)d_in[28]; const float* cb1=(const float*)d_in[29];
  const float* cw2=(const float*)d_in[30]; const float* cb2=(const float*)d_in[31];
  const float* coordw=(const float*)d_in[32];
  const float* xw1=(const float*)d_in[33]; const float* xb1=(const float*)d_in[34];
  const float* xw2=(const float*)d_in[35]; const float* xb2=(const float*)d_in[36];

  // workspace layout (bytes), high-water = 103,829,472 (unchanged)
  char* B = (char*)d_ws;
  float* eattn = (float*)(B + 0);                        // E*4*4   = 12,800,000
  float* cvec  = (float*)(B + 12800000);                 // E*3*4   =  9,600,000
  float* stats = (float*)(B + 22400000);                 // 64 (stats[12..15] = folded ewt bias)
  float* asum  = (float*)(B + 22400064);                 // N*4*4   =    800,000
  int* counts  = (int*)(B + 23200064);                   // N*4     =    200,000  (also cursor)
  int* offs    = (int*)(B + 23400064);                   // (N+1)*4 =    200,004
  unsigned short* wfrag = (unsigned short*)(B + 23600080); // frag region 212,992 B
  int* elist   = (int*)(B + 23813088);                   // E*4     =  3,200,000
  unsigned short* qb = (unsigned short*)(B + 27013088);  // N*256*2 = 25,600,000
  unsigned short* kb = (unsigned short*)(B + 52613088);  // N*256*2 = 25,600,000
  unsigned short* vb = (unsigned short*)(B + 78213088);  // N*256*2 = 25,600,000
  unsigned short* whfrag = (unsigned short*)(B + 103813088); // 4*2048 bf16 = 16,384
  float* fbias = (float*)(wfrag + 73728);                // 388 f32 (persistent)
  unsigned short* wof = wfrag + 74752;                   // Wo frag, 16,384 shorts (ends 91,136 < 106,496)
  // wv [N][256] bf16 reuses qb (dead after k_e1)
  unsigned short* wv = qb;
  // f32 fold staging in elist region (consumed before k_fill)
  float* wcomb = (float*)elist;                          // 512
  float* wgf   = wcomb + 512;                            // 512
  float* wmf   = wgf + 512;                              // 161*128 = 20,608
  float* wcf   = wmf + 20608;                            // 16,384
  float* wxf   = wcf + 16384;                            // 16,384
  unsigned short* qkvf = (unsigned short*)eattn;         // 48 tiles x 1024 shorts

  k_zero<<<977,256,0,stream>>>(stats, 250016);
  // folds
  k_wcomb<<<1,256,0,stream>>>(ew2, eww, eb2, ewb, pb2, wcomb, stats);
  k_wfoldm<<<81,256,0,stream>>>(ew2, mw1, eb2, mb1, wmf, fbias + 0);
  k_wfold<<<65,256,0,stream>>>(mw2, cw1, mb2, cb1, wcf, fbias + 128);
  k_wfold<<<65,256,0,stream>>>(mw2, xw1, mb2, xb1, wxf, fbias + 256);
  k_wfoldg<<<3,256,0,stream>>>(mw2, gw, mb2, gb, wgf, fbias + 384);
  // frag prep
  k_wprep<<<80,256,0,stream>>>(ew1, wfrag + 0,     135, 5);
  k_wprep<<<80,256,0,stream>>>(wmf, wfrag + 20480, 160, 5);
  k_wprep<<<64,256,0,stream>>>(wcf, wfrag + 40960, 128, 4);
  k_wprep<<<64,256,0,stream>>>(wxf, wfrag + 57344, 128, 4);
  k_wprepq<<<64,256,0,stream>>>(Wq, qkvf + 0);
  k_wprepq<<<64,256,0,stream>>>(Wk, qkvf + 16384);
  k_wprepq<<<64,256,0,stream>>>(Wv, qkvf + 32768);
  k_wprepo<<<64,256,0,stream>>>(Wo, wof);
  k_wprep4<<<8,256,0,stream>>>(wcomb, whfrag + 0);
  k_wprep4<<<8,256,0,stream>>>(wgf, whfrag + 2048);
  k_wprep4<<<8,256,0,stream>>>(cw2, whfrag + 4096);
  k_wprep4<<<8,256,0,stream>>>(xw2, whfrag + 6144);

  k_stats<<<196,256,0,stream>>>(x, stats);
  k_statsfin<<<1,64,0,stream>>>(stats);
  k_qkv2<<<782,256,0,stream>>>(h, qkvf, bq, bk, bv, qb, kb, vb);
  k_count<<<3125,256,0,stream>>>(ei,counts);
  k_scan<<<1,256,0,stream>>>(counts,offs);
  k_fill<<<3125,256,0,stream>>>(ei,counts,elist);
  k_e1<<<12500,512,0,stream>>>(h,x,ei,stats,qb,kb,wfrag,whfrag,eb1,pw1,pb1,pw2,asum,eattn);
  k_e2<<<12500,512,0,stream>>>(h,x,ei,stats,asum,eattn,wfrag,whfrag,eb1,fbias,cb2,coordw,xb2,cvec);
  k_agg<<<12500,256,0,stream>>>(ei,offs,elist,eattn,vb,cvec,asum,wv,(float*)d_out);
  k_out<<<782,256,0,stream>>>(wv,wof,bo,(float*)d_out);
}